// Round 4
// baseline (614.091 us; speedup 1.0000x reference)
//
#include <hip/hip_runtime.h>

// EMA Vector-Quantizer for MI355X (gfx950).
// N=16384 tokens, D=64, K=8192.
// R17-R19 (fp32 VALU distance GEMM): plateau 203us, VALUBusy 75%, MfmaUtil 0
// -- 103 TF VALU pipe is the structural ceiling (no fp32 MFMA on CDNA4).
// R20 (failed): bf16 hi/lo split GEMM. Outputs 0/1 passed (layout + argmin
// path verified); output 2 failed 3.8e5 = empty-cluster amplification.
// Root cause: enc atomics in k_reduce used PRE-refine idx; k_refine then
// changed idx -> cluster counts inconsistent with embed sums. Also latent:
// [zh|zl].[wh|wl] misses cross terms zh.wl+zl.wh (~0.03 dist error tail).
// R21 (this): (1) enc moved to k_enc AFTER refine (final idx); (2) cross
// terms added with the same loaded fragments: acc = a0b0+a1b1+a2b2+a3b3
// + a0b2+a1b3+a2b0+a3b1 = (zh+zl).(wh+wl). Residual dist error vs fp32
// ~1.5e-3 worst (2^-18 repr + accum order); MARGIN=0.03 -> 10x headroom.
// Safety net: exact 2nd-best tracking (2-min merge exact); computed gap <
// MARGIN => exact fp32 recompute in k_refine. Unflagged provably match ref.
// Scratch plan (out buffer, 8.4MB):
//   A' bf16[16384][128] -> z_q region bytes [0,4MB)        (dead after GEMM)
//   B' bf16[8192][128]  -> byte 4227072 (16B-aligned, spans W tail + CS)
//                          (dead after GEMM; CS re-zeroed, W by k_final)
//   cand (d1,i1,d2)[8][16384] -> EA region (scalar access; EA base 4B-align)
//   flag list -> z_q ints [0,16384) (post-GEMM, dead before k_quant)
// Predicted: k_argmin 25-45us, MfmaUtil 15-25%, total ~160-200us.

#define N_TOK 16384
#define K_EMB 8192
#define EMB_D 64
#define GROUPS 8

typedef short bf8 __attribute__((ext_vector_type(8)));
typedef float f32x4 __attribute__((ext_vector_type(4)));
typedef unsigned short us4 __attribute__((ext_vector_type(4)));

// d_out flat layout (float32), reference return order:
// z_q (1048576) | loss | new_weight (524288) | new_cluster_size (8192) | new_embed_avg (524288)
#define OFF_LOSS 1048576
#define OFF_W    1048577
#define OFF_CS   1572865
#define OFF_EA   1581057

// scratch offsets
#define B_BASE   2113536   // ushort index into out = byte 4227072 (16B aligned)
#define CAND_I1  131072    // within EA-based cand area (floats/ints)
#define CAND_D2  262144

#define MARGIN 0.03f

// ws float offsets
#define WS_NSUM  0
#define WS_LOSS  1
#define WS_FCNT  2        // int
#define WS_WNORM 16
#define WS_IDX   (WS_WNORM + K_EMB)

__device__ __forceinline__ unsigned short f2bf(float x) {
  unsigned int b = __float_as_uint(x);
  return (unsigned short)((b + 0x7fff + ((b >> 16) & 1)) >> 16);
}
__device__ __forceinline__ float bf2f(unsigned short h) {
  return __uint_as_float(((unsigned int)h) << 16);
}

// ---------------------------------------------------------------------------
// K0: wnorm[k]; B' = [bf16_hi | bf16_lo] per code row; zero ws scalars.
__global__ void k_prep(const float* __restrict__ weight,
                       float* __restrict__ out, float* __restrict__ ws) {
  int gid = blockIdx.x * 256 + threadIdx.x;     // 0..131071
  int row = gid >> 4;                            // codebook row 0..8191
  int l16 = gid & 15;
  float4 w4 = *(const float4*)(weight + row * EMB_D + l16 * 4);
  float s = w4.x * w4.x + w4.y * w4.y + w4.z * w4.z + w4.w * w4.w;
  #pragma unroll
  for (int off = 8; off > 0; off >>= 1) s += __shfl_xor(s, off, 16);
  if (l16 == 0) ws[WS_WNORM + row] = s;

  float wv[4] = {w4.x, w4.y, w4.z, w4.w};
  us4 hi, lo;
  #pragma unroll
  for (int e = 0; e < 4; ++e) {
    unsigned short h = f2bf(wv[e]);
    hi[e] = h;
    lo[e] = f2bf(wv[e] - bf2f(h));
  }
  unsigned short* bp = (unsigned short*)out + B_BASE + row * 128 + l16 * 4;
  *(us4*)bp = hi;           // k = d (0..63)
  *(us4*)(bp + 64) = lo;    // k = 64 + d

  if (gid == 0) {
    out[OFF_LOSS] = 0.f; ws[WS_NSUM] = 0.f; ws[WS_LOSS] = 0.f;
    ((int*)ws)[WS_FCNT] = 0;
  }
}

// ---------------------------------------------------------------------------
// K0b: A' = [bf16_hi | bf16_lo] per token row, via LDS transpose.
// z is (b,c,hw): z_flat[n][d] = z[b*65536 + d*1024 + hw], n = b*1024+hw.
__global__ void k_prep_a(const float* __restrict__ z, float* __restrict__ out) {
  __shared__ float z_s[EMB_D * 256];
  const int t = threadIdx.x;
  const int b = blockIdx.x >> 2;
  const int hw0 = (blockIdx.x & 3) * 256;
  const float* zb = z + b * 65536 + hw0;
  #pragma unroll
  for (int i = 0; i < 16; ++i) {
    int f4 = i * 256 + t;
    int d = f4 >> 6, c4 = (f4 & 63) * 4;
    *(float4*)(z_s + d * 256 + c4) = *(const float4*)(zb + d * 1024 + c4);
  }
  __syncthreads();
  int tok = b * 1024 + hw0 + t;
  unsigned short* ap = (unsigned short*)out + tok * 128;
  #pragma unroll
  for (int j = 0; j < 16; ++j) {          // 16 groups of 4 d-values
    us4 hi, lo;
    #pragma unroll
    for (int e = 0; e < 4; ++e) {
      float zv = z_s[(j * 4 + e) * 256 + t];
      unsigned short h = f2bf(zv);
      hi[e] = h;
      lo[e] = f2bf(zv - bf2f(h));
    }
    *(us4*)(ap + j * 4) = hi;
    *(us4*)(ap + 64 + j * 4) = lo;
  }
}

// ---------------------------------------------------------------------------
// K1: distance argmin on the matrix pipe. Block = 4 waves: (tw,cw) in 2x2;
// wave covers 64 tokens x 512 codes; block = 128 tokens x 1024 codes (one
// k-group). grid (128, 8). Per 16-code subtile: 4 global b-frag loads (16B,
// L2-hot) + 8 mfma per token-tile (direct + cross terms) + per-lane
// (d1,i1,d2) update. A-frags (64 VGPR) loaded once. C layout: col=lane&15
// (code), row=(lane>>4)*4+reg (token) [m89-verified].
__global__ __launch_bounds__(256, 3) void k_argmin(
    const short* __restrict__ A, const short* __restrict__ B,
    const float* __restrict__ wnorm, float* __restrict__ cand) {
  __shared__ float m_d1[2][128], m_d2[2][128];
  __shared__ int   m_i1[2][128];
  const int t = threadIdx.x;
  const int lane = t & 63;
  const int wid = __builtin_amdgcn_readfirstlane(t >> 6);  // 0..3
  const int tw = wid >> 1, cw = wid & 1;
  const int trow0 = blockIdx.x * 128 + tw * 64;
  const int g = blockIdx.y;
  const int cg0 = g * 1024 + cw * 512;
  const int lr = lane & 15, lq = lane >> 4;

  // a0,a1 = zh halves (k 0..31, 32..63); a2,a3 = zl halves.
  bf8 a[4][4];                             // [token-tile][k-step]
  #pragma unroll
  for (int tt = 0; tt < 4; ++tt) {
    const short* ap = A + (trow0 + tt * 16 + lr) * 128 + lq * 8;
    #pragma unroll
    for (int s = 0; s < 4; ++s) a[tt][s] = *(const bf8*)(ap + s * 32);
  }

  float d1[16], d2[16]; int i1[16];
  #pragma unroll
  for (int v = 0; v < 16; ++v) { d1[v] = 3.4e38f; d2[v] = 3.4e38f; i1[v] = 0; }

  for (int cs = 0; cs < 32; ++cs) {
    const int code = cg0 + cs * 16 + lr;
    const short* bp = B + code * 128 + lq * 8;
    bf8 b0 = *(const bf8*)(bp);            // wh k 0..31
    bf8 b1 = *(const bf8*)(bp + 32);       // wh k 32..63
    bf8 b2 = *(const bf8*)(bp + 64);       // wl k 0..31
    bf8 b3 = *(const bf8*)(bp + 96);       // wl k 32..63
    float wn = wnorm[code];

    f32x4 acc[4];
    #pragma unroll
    for (int tt = 0; tt < 4; ++tt) acc[tt] = (f32x4)(0.f);
    #pragma unroll
    for (int tt = 0; tt < 4; ++tt) {
      // direct: zh.wh + zl.wl
      acc[tt] = __builtin_amdgcn_mfma_f32_16x16x32_bf16(a[tt][0], b0, acc[tt], 0, 0, 0);
      acc[tt] = __builtin_amdgcn_mfma_f32_16x16x32_bf16(a[tt][1], b1, acc[tt], 0, 0, 0);
      acc[tt] = __builtin_amdgcn_mfma_f32_16x16x32_bf16(a[tt][2], b2, acc[tt], 0, 0, 0);
      acc[tt] = __builtin_amdgcn_mfma_f32_16x16x32_bf16(a[tt][3], b3, acc[tt], 0, 0, 0);
      // cross: zh.wl + zl.wh  -> total = (zh+zl).(wh+wl)
      acc[tt] = __builtin_amdgcn_mfma_f32_16x16x32_bf16(a[tt][0], b2, acc[tt], 0, 0, 0);
      acc[tt] = __builtin_amdgcn_mfma_f32_16x16x32_bf16(a[tt][1], b3, acc[tt], 0, 0, 0);
      acc[tt] = __builtin_amdgcn_mfma_f32_16x16x32_bf16(a[tt][2], b0, acc[tt], 0, 0, 0);
      acc[tt] = __builtin_amdgcn_mfma_f32_16x16x32_bf16(a[tt][3], b1, acc[tt], 0, 0, 0);
    }
    #pragma unroll
    for (int tt = 0; tt < 4; ++tt)
      #pragma unroll
      for (int r = 0; r < 4; ++r) {
        const int v = tt * 4 + r;
        float d = fmaf(-2.f, acc[tt][r], wn);
        bool lt = d < d1[v];
        d2[v] = lt ? d1[v] : fminf(d2[v], d);
        d1[v] = lt ? d : d1[v];
        i1[v] = lt ? code : i1[v];
      }
  }

  // exact 2-min merge across the 16 code-columns (lanes sharing lq)
  #pragma unroll
  for (int m = 1; m < 16; m <<= 1) {
    #pragma unroll
    for (int v = 0; v < 16; ++v) {
      float od1 = __shfl_xor(d1[v], m, 64);
      float od2 = __shfl_xor(d2[v], m, 64);
      int   oi1 = __shfl_xor(i1[v], m, 64);
      d2[v] = fminf(fminf(d2[v], od2), fmaxf(d1[v], od1));
      bool take = (od1 < d1[v]) || (od1 == d1[v] && oi1 < i1[v]);
      d1[v] = take ? od1 : d1[v];
      i1[v] = take ? oi1 : i1[v];
    }
  }

  if (lr == 0) {
    #pragma unroll
    for (int tt = 0; tt < 4; ++tt)
      #pragma unroll
      for (int r = 0; r < 4; ++r) {
        int v = tt * 4 + r;
        int tl = tw * 64 + tt * 16 + lq * 4 + r;
        m_d1[cw][tl] = d1[v]; m_d2[cw][tl] = d2[v]; m_i1[cw][tl] = i1[v];
      }
  }
  __syncthreads();
  if (t < 128) {
    float x1 = m_d1[0][t], y1 = m_d1[1][t];
    float x2 = m_d2[0][t], y2 = m_d2[1][t];
    int   xi = m_i1[0][t], yi = m_i1[1][t];
    float D2 = fminf(fminf(x2, y2), fmaxf(x1, y1));
    bool take = (y1 < x1) || (y1 == x1 && yi < xi);
    float D1 = take ? y1 : x1;
    int   I1 = take ? yi : xi;
    int token = blockIdx.x * 128 + t;
    cand[g * N_TOK + token] = D1;
    ((int*)cand)[CAND_I1 + g * N_TOK + token] = I1;
    cand[CAND_D2 + g * N_TOK + token] = D2;
  }
}

// ---------------------------------------------------------------------------
// K1b: zero cluster-size accumulators (B' overlapped CS; B' is dead now).
__global__ void k_zcs(float* __restrict__ out) {
  out[OFF_CS + blockIdx.x * 256 + threadIdx.x] = 0.f;
}

// ---------------------------------------------------------------------------
// K2: merge GROUPS candidates (exact 2-min); idx + margin flags.
// NO enc atomics here -- enc must use the POST-refine idx (R20 bug).
__global__ void k_reduce(const float* __restrict__ cand, int* __restrict__ idx,
                         int* __restrict__ flags, int* __restrict__ fcnt) {
  int n = blockIdx.x * 256 + threadIdx.x;
  const int* ci = (const int*)cand + CAND_I1;
  float D1 = cand[n]; int I1 = ci[n]; float D2 = cand[CAND_D2 + n];
  #pragma unroll
  for (int g = 1; g < GROUPS; ++g) {
    float d = cand[g * N_TOK + n];
    int   i = ci[g * N_TOK + n];
    float dd = cand[CAND_D2 + g * N_TOK + n];
    D2 = fminf(fminf(D2, dd), fmaxf(D1, d));
    bool take = (d < D1) || (d == D1 && i < I1);
    D1 = take ? d : D1; I1 = take ? i : I1;
  }
  idx[n] = I1;
  if (D2 - D1 < MARGIN) {
    int p = atomicAdd(fcnt, 1);
    flags[p] = n;
  }
}

// ---------------------------------------------------------------------------
// K2b: exact fp32 argmin for flagged tokens (same fma chain as R19 kernel).
__global__ void k_refine(const float* __restrict__ z, const float* __restrict__ weight,
                         const float* __restrict__ wnorm, const int* __restrict__ flags,
                         const int* __restrict__ fcnt, int* __restrict__ idx) {
  __shared__ float zt[EMB_D];
  __shared__ float rd[256];
  __shared__ int   ri[256];
  int cnt = *fcnt;
  for (int f = blockIdx.x; f < cnt; f += gridDim.x) {
    int n = flags[f];
    int b = n >> 10, hw = n & 1023;
    if (threadIdx.x < EMB_D) zt[threadIdx.x] = z[b * 65536 + threadIdx.x * 1024 + hw];
    __syncthreads();
    float bd = 3.4e38f; int bi = 0x7fffffff;
    for (int k = threadIdx.x; k < K_EMB; k += 256) {
      const float* wr = weight + k * EMB_D;
      float dot = 0.f;
      for (int d = 0; d < EMB_D; ++d) dot = fmaf(zt[d], wr[d], dot);
      float dist = fmaf(-2.f, dot, wnorm[k]);
      if (dist < bd || (dist == bd && k < bi)) { bd = dist; bi = k; }
    }
    rd[threadIdx.x] = bd; ri[threadIdx.x] = bi;
    __syncthreads();
    for (int s2 = 128; s2 > 0; s2 >>= 1) {
      if (threadIdx.x < s2) {
        float od = rd[threadIdx.x + s2]; int oi = ri[threadIdx.x + s2];
        if (od < rd[threadIdx.x] || (od == rd[threadIdx.x] && oi < ri[threadIdx.x])) {
          rd[threadIdx.x] = od; ri[threadIdx.x] = oi;
        }
      }
      __syncthreads();
    }
    if (threadIdx.x == 0) idx[n] = ri[0];
    __syncthreads();
  }
}

// ---------------------------------------------------------------------------
// K2c: enc counts from FINAL idx (after refine; CS already zeroed by k_zcs).
__global__ void k_enc(const int* __restrict__ idx, float* __restrict__ enc) {
  int n = blockIdx.x * 256 + threadIdx.x;
  atomicAdd(enc + idx[n], 1.0f);
}

// ---------------------------------------------------------------------------
// K2d: zero embed-avg accumulators (cand lived here; cand is dead now).
// EA base is only 4B-aligned -> scalar stores.
__global__ void k_zea(float* __restrict__ out) {
  int base = OFF_EA + blockIdx.x * 1024;
  #pragma unroll
  for (int j = 0; j < 4; ++j) out[base + j * 256 + threadIdx.x] = 0.f;
}

// ---------------------------------------------------------------------------
// K3: z_q gather + straight-through output + loss partials + embed_sum atomics.
__global__ void k_quant(const float* __restrict__ z, const float* __restrict__ weight,
                        const int* __restrict__ idx, float* __restrict__ out,
                        float* __restrict__ embed_acc, float* __restrict__ ws) {
  int base = blockIdx.x * 1024 + threadIdx.x;
  float lsum = 0.f;
  #pragma unroll
  for (int i = 0; i < 4; ++i) {
    int e = base + i * 256;               // (b,c,hw) flat, same layout as z
    int c = (e >> 10) & 63;
    int n = ((e >> 16) << 10) | (e & 1023);
    int k = idx[n];
    float zv = z[e];
    float q = weight[k * EMB_D + c];
    out[e] = zv + (q - zv);               // straight-through value
    float d = q - zv;
    lsum += d * d;
    atomicAdd(embed_acc + k * EMB_D + c, zv);
  }
  #pragma unroll
  for (int off = 32; off > 0; off >>= 1) lsum += __shfl_xor(lsum, off, 64);
  __shared__ float red[4];
  int lane = threadIdx.x & 63, wv = threadIdx.x >> 6;
  if (lane == 0) red[wv] = lsum;
  __syncthreads();
  if (threadIdx.x == 0)
    atomicAdd(ws + WS_LOSS, red[0] + red[1] + red[2] + red[3]);
}

// ---------------------------------------------------------------------------
// K4: new_cluster_size (in place over enc_sum), n-sum, loss finalize.
__global__ void k_cluster(const float* __restrict__ cluster_in,
                          float* __restrict__ out, float* __restrict__ ws) {
  int k = blockIdx.x * 256 + threadIdx.x;
  float ncs = cluster_in[k] * 0.99f + 0.01f * out[OFF_CS + k];
  out[OFF_CS + k] = ncs;
  float s = ncs;
  #pragma unroll
  for (int off = 32; off > 0; off >>= 1) s += __shfl_xor(s, off, 64);
  __shared__ float red[4];
  int lane = threadIdx.x & 63, wv = threadIdx.x >> 6;
  if (lane == 0) red[wv] = s;
  __syncthreads();
  if (threadIdx.x == 0) atomicAdd(ws + WS_NSUM, red[0] + red[1] + red[2] + red[3]);
  if (blockIdx.x == 0 && threadIdx.x == 0)
    out[OFF_LOSS] = 0.25f * ws[WS_LOSS] * (1.0f / 1048576.0f);
}

// ---------------------------------------------------------------------------
// K5: smoothed cluster sizes -> new_weight; new_embed_avg (in place).
__global__ void k_final(const float* __restrict__ embed_avg,
                        float* __restrict__ out, const float* __restrict__ ws) {
  int e = blockIdx.x * 256 + threadIdx.x;   // < 524288
  int k = e >> 6;
  float ncs = out[OFF_CS + k];
  float nsum = ws[WS_NSUM];
  float sm = (ncs + 1e-5f) / (nsum + K_EMB * 1e-5f) * nsum;
  float ea = embed_avg[e] * 0.99f + 0.01f * out[OFF_EA + e];
  out[OFF_EA + e] = ea;
  out[OFF_W + e] = ea / sm;
}

// ---------------------------------------------------------------------------
extern "C" void kernel_launch(void* const* d_in, const int* in_sizes, int n_in,
                              void* d_out, int out_size, void* d_ws, size_t ws_size,
                              hipStream_t stream) {
  const float* z = (const float*)d_in[0];
  const float* weight = (const float*)d_in[1];
  const float* cluster = (const float*)d_in[2];
  const float* embed_avg = (const float*)d_in[3];
  float* out = (float*)d_out;
  float* ws = (float*)d_ws;
  float* wnorm = ws + WS_WNORM;
  int* idx = (int*)(ws + WS_IDX);
  int* fcnt = (int*)ws + WS_FCNT;
  const short* Ap = (const short*)out;                     // A' in z_q region
  const short* Bp = (const short*)((unsigned short*)out + B_BASE);
  float* cand = out + OFF_EA;
  int* flags = (int*)out;                                  // z_q region ints

  hipLaunchKernelGGL(k_prep, dim3(512), dim3(256), 0, stream, weight, out, ws);
  hipLaunchKernelGGL(k_prep_a, dim3(64), dim3(256), 0, stream, z, out);
  hipLaunchKernelGGL(k_argmin, dim3(N_TOK / 128, GROUPS), dim3(256), 0, stream,
                     Ap, Bp, wnorm, cand);
  hipLaunchKernelGGL(k_zcs, dim3(K_EMB / 256), dim3(256), 0, stream, out);
  hipLaunchKernelGGL(k_reduce, dim3(N_TOK / 256), dim3(256), 0, stream,
                     cand, idx, flags, fcnt);
  hipLaunchKernelGGL(k_refine, dim3(64), dim3(256), 0, stream,
                     z, weight, wnorm, flags, fcnt, idx);
  hipLaunchKernelGGL(k_enc, dim3(N_TOK / 256), dim3(256), 0, stream,
                     idx, out + OFF_CS);
  hipLaunchKernelGGL(k_zea, dim3(512), dim3(256), 0, stream, out);
  hipLaunchKernelGGL(k_quant, dim3(1024), dim3(256), 0, stream,
                     z, weight, idx, out, out + OFF_EA, ws);
  hipLaunchKernelGGL(k_cluster, dim3(K_EMB / 256), dim3(256), 0, stream,
                     cluster, out, ws);
  hipLaunchKernelGGL(k_final, dim3(524288 / 256), dim3(256), 0, stream,
                     embed_avg, out, ws);
}

// Round 6
// 395.589 us; speedup vs baseline: 1.5523x; 1.5523x over previous
//
#include <hip/hip_runtime.h>

// EMA Vector-Quantizer for MI355X (gfx950).
// N=16384 tokens, D=64, K=8192.
// R17-R19: fp32 VALU distance GEMM plateau 203us (no fp32 MFMA on CDNA4).
// R20/R21: bf16 hi/lo split GEMM (dot = (zh+zl).(wh+wl), 8 MFMAs incl cross
// terms; exact 2nd-best margin + fp32 refine safety net). R21 passed; 307us
// k_argmin with 492MB WRITE (register spill, demand ~150 vs 84 granted).
// R22 (failed): spill-proof tiling + LDS-staged B'' was CORRECT (z_q/loss
// passed) but CS zeroing was folded into k_prep while B'' overlaps the CS
// region -> B'' tail overwrote the zeroed CS; k_enc accumulated counts on
// bf16 garbage (1.3e8). R23 (this): restore k_zcs as its own kernel AFTER
// k_argmin (B'' dead), before k_reduce/k_enc. No other changes.
// k_argmin structure (R22): wave = 32 tokens (a[2][4]=32 VGPR, best 8x3=24,
// acc[2]=8 -> ~95 peak < 128 cap at launch_bounds(256,4)); waves split
// tokens, no cross-wave merge; B panel staged via global_load_lds in 4KB
// 16-code chunks, double-buffered, layout [chunk][seg][lq][code] so DMA is
// linear and ds_read_b128 conflict-free; XCD swizzle g=bid&7 keeps each
// group's 256KB panel L2-resident; wnorm staged to LDS once.
// Predicted: k_argmin WRITE 492MB->~3MB, dur 30-60us, total ~300-340us.

#define N_TOK 16384
#define K_EMB 8192
#define EMB_D 64
#define GROUPS 8

typedef short bf8 __attribute__((ext_vector_type(8)));
typedef float f32x4 __attribute__((ext_vector_type(4)));
typedef unsigned short us4 __attribute__((ext_vector_type(4)));

// d_out flat layout (float32), reference return order:
// z_q (1048576) | loss | new_weight (524288) | new_cluster_size (8192) | new_embed_avg (524288)
#define OFF_LOSS 1048576
#define OFF_W    1048577
#define OFF_CS   1572865
#define OFF_EA   1581057

// scratch offsets
#define B_BASE   2113536   // ushort index into out = byte 4227072 (16B aligned)
                           // B'' = 2MB = floats [1056768, 1581056): W tail + CS.
                           // CS re-zeroed by k_zcs AFTER k_argmin (R22 lesson).
#define CAND_I1  131072    // within EA-based cand area (floats/ints)
#define CAND_D2  262144

#define MARGIN 0.03f

// ws float offsets
#define WS_NSUM  0
#define WS_LOSS  1
#define WS_FCNT  2        // int
#define WS_WNORM 16
#define WS_IDX   (WS_WNORM + K_EMB)

__device__ __forceinline__ unsigned short f2bf(float x) {
  unsigned int b = __float_as_uint(x);
  return (unsigned short)((b + 0x7fff + ((b >> 16) & 1)) >> 16);
}
__device__ __forceinline__ float bf2f(unsigned short h) {
  return __uint_as_float(((unsigned int)h) << 16);
}

// async global->LDS, 16B per lane (dest = wave-uniform base + lane*16)
__device__ __forceinline__ void gload16(const void* g, void* l) {
  __builtin_amdgcn_global_load_lds(
      (const __attribute__((address_space(1))) void*)g,
      (__attribute__((address_space(3))) void*)l, 16, 0, 0);
}

// ---------------------------------------------------------------------------
// K0: wnorm[k]; B'' chunk layout [chunk][seg][lq][code] (shorts); ws scalars.
// Chunk = 16 codes = 2048 shorts; seg s (0..3) = [wh k0-31|wh k32-63|
// wl k0-31|wl k32-63]; within seg: lq (k%32/8) * 128 + code*8 + k%8.
__global__ void k_prep(const float* __restrict__ weight,
                       float* __restrict__ out, float* __restrict__ ws) {
  int gid = blockIdx.x * 256 + threadIdx.x;     // 0..131071
  int row = gid >> 4;                            // codebook row 0..8191
  int l16 = gid & 15;
  float4 w4 = *(const float4*)(weight + row * EMB_D + l16 * 4);
  float s = w4.x * w4.x + w4.y * w4.y + w4.z * w4.z + w4.w * w4.w;
  #pragma unroll
  for (int off = 8; off > 0; off >>= 1) s += __shfl_xor(s, off, 16);
  if (l16 == 0) ws[WS_WNORM + row] = s;

  float wv[4] = {w4.x, w4.y, w4.z, w4.w};
  us4 hi, lo;
  #pragma unroll
  for (int e = 0; e < 4; ++e) {
    unsigned short h = f2bf(wv[e]);
    hi[e] = h;
    lo[e] = f2bf(wv[e] - bf2f(h));
  }
  // d0..d0+3 land in seg sp (hi) / 2+sp (lo), slot lqp, j = jj..jj+3
  int d0 = l16 * 4;
  int jj = d0 & 7;                 // 0 or 4
  int lqp = (d0 >> 3) & 3;
  int sp = d0 >> 5;                // 0 or 1
  unsigned short* bp = (unsigned short*)out + B_BASE
      + (row >> 4) * 2048 + (row & 15) * 8 + lqp * 128 + jj;
  *(us4*)(bp + sp * 512) = hi;
  *(us4*)(bp + (2 + sp) * 512) = lo;

  if (gid == 0) {
    out[OFF_LOSS] = 0.f; ws[WS_NSUM] = 0.f; ws[WS_LOSS] = 0.f;
    ((int*)ws)[WS_FCNT] = 0;
  }
}

// ---------------------------------------------------------------------------
// K0b: A' = [bf16_hi | bf16_lo] per token row, via LDS transpose.
// z is (b,c,hw): z_flat[n][d] = z[b*65536 + d*1024 + hw], n = b*1024+hw.
__global__ void k_prep_a(const float* __restrict__ z, float* __restrict__ out) {
  __shared__ float z_s[EMB_D * 256];
  const int t = threadIdx.x;
  const int b = blockIdx.x >> 2;
  const int hw0 = (blockIdx.x & 3) * 256;
  const float* zb = z + b * 65536 + hw0;
  #pragma unroll
  for (int i = 0; i < 16; ++i) {
    int f4 = i * 256 + t;
    int d = f4 >> 6, c4 = (f4 & 63) * 4;
    *(float4*)(z_s + d * 256 + c4) = *(const float4*)(zb + d * 1024 + c4);
  }
  __syncthreads();
  int tok = b * 1024 + hw0 + t;
  unsigned short* ap = (unsigned short*)out + tok * 128;
  #pragma unroll
  for (int j = 0; j < 16; ++j) {          // 16 groups of 4 d-values
    us4 hi, lo;
    #pragma unroll
    for (int e = 0; e < 4; ++e) {
      float zv = z_s[(j * 4 + e) * 256 + t];
      unsigned short h = f2bf(zv);
      hi[e] = h;
      lo[e] = f2bf(zv - bf2f(h));
    }
    *(us4*)(ap + j * 4) = hi;
    *(us4*)(ap + 64 + j * 4) = lo;
  }
}

// ---------------------------------------------------------------------------
// K1: distance argmin on the matrix pipe, LDS-staged B, spill-proof tiling.
// Grid 1024 blocks 1-D; g = bid&7 (XCD swizzle: one k-group per XCD),
// tok_blk = bid>>3. Block = 4 waves x 32 tokens = 128 tokens, scanning all
// 1024 codes of group g in 64 chunks of 16. Per chunk: 1 gload16/thread
// stages next 4KB; 4 conflict-free ds_read_b128 b-frags; 16 MFMAs
// (2 token-tiles x (4 direct + 4 cross)); exact (d1,i1,d2) update.
// C layout: col=lane&15 (code), row=(lane>>4)*4+reg (token) [m89-verified].
__global__ __launch_bounds__(256, 4) void k_argmin(
    const short* __restrict__ A, const short* __restrict__ B,
    const float* __restrict__ wnorm, float* __restrict__ cand) {
  __shared__ __align__(16) short wbuf[2][2048];   // 2 x 4KB chunk dbuf
  __shared__ __align__(16) float wn_s[1024];      // group wnorm
  const int t = threadIdx.x;
  const int lane = t & 63;
  const int wid = __builtin_amdgcn_readfirstlane(t >> 6);  // 0..3
  const int g = blockIdx.x & 7;
  const int tok_blk = blockIdx.x >> 3;
  const int trow0 = tok_blk * 128 + wid * 32;
  const int lr = lane & 15, lq = lane >> 4;

  // A-frags: 2 token-tiles x 4 k-segs (zh k0-31, zh k32-63, zl k0-31, zl k32-63)
  bf8 a[2][4];
  #pragma unroll
  for (int tt = 0; tt < 2; ++tt) {
    const short* ap = A + (size_t)(trow0 + tt * 16 + lr) * 128 + lq * 8;
    #pragma unroll
    for (int s = 0; s < 4; ++s) a[tt][s] = *(const bf8*)(ap + s * 32);
  }

  const short* bsrc = B + (size_t)g * 64 * 2048;  // group panel: 64 chunks

  // stage wnorm (4KB) + chunk 0
  *(float4*)(wn_s + t * 4) = *(const float4*)(wnorm + g * 1024 + t * 4);
  gload16(bsrc + t * 8, &wbuf[0][0] + t * 8);
  asm volatile("s_waitcnt vmcnt(0)" ::: "memory");
  __syncthreads();

  float d1[8], d2[8]; int i1[8];
  #pragma unroll
  for (int v = 0; v < 8; ++v) { d1[v] = 3.4e38f; d2[v] = 3.4e38f; i1[v] = 0; }

  for (int c = 0; c < 64; ++c) {
    if (c + 1 < 64)
      gload16(bsrc + (c + 1) * 2048 + t * 8, &wbuf[(c + 1) & 1][0] + t * 8);

    const short* cb = &wbuf[c & 1][0];
    bf8 bfr[4];
    #pragma unroll
    for (int s = 0; s < 4; ++s)
      bfr[s] = *(const bf8*)(cb + s * 512 + lq * 128 + lr * 8);
    float wn = wn_s[c * 16 + lr];

    f32x4 acc[2];
    acc[0] = (f32x4)(0.f); acc[1] = (f32x4)(0.f);
    #pragma unroll
    for (int tt = 0; tt < 2; ++tt) {
      // direct: zh.wh + zl.wl
      acc[tt] = __builtin_amdgcn_mfma_f32_16x16x32_bf16(a[tt][0], bfr[0], acc[tt], 0, 0, 0);
      acc[tt] = __builtin_amdgcn_mfma_f32_16x16x32_bf16(a[tt][1], bfr[1], acc[tt], 0, 0, 0);
      acc[tt] = __builtin_amdgcn_mfma_f32_16x16x32_bf16(a[tt][2], bfr[2], acc[tt], 0, 0, 0);
      acc[tt] = __builtin_amdgcn_mfma_f32_16x16x32_bf16(a[tt][3], bfr[3], acc[tt], 0, 0, 0);
      // cross: zh.wl + zl.wh  -> total = (zh+zl).(wh+wl)
      acc[tt] = __builtin_amdgcn_mfma_f32_16x16x32_bf16(a[tt][0], bfr[2], acc[tt], 0, 0, 0);
      acc[tt] = __builtin_amdgcn_mfma_f32_16x16x32_bf16(a[tt][1], bfr[3], acc[tt], 0, 0, 0);
      acc[tt] = __builtin_amdgcn_mfma_f32_16x16x32_bf16(a[tt][2], bfr[0], acc[tt], 0, 0, 0);
      acc[tt] = __builtin_amdgcn_mfma_f32_16x16x32_bf16(a[tt][3], bfr[1], acc[tt], 0, 0, 0);
    }

    const int code = g * 1024 + c * 16 + lr;
    #pragma unroll
    for (int tt = 0; tt < 2; ++tt)
      #pragma unroll
      for (int r = 0; r < 4; ++r) {
        const int v = tt * 4 + r;
        float d = fmaf(-2.f, acc[tt][r], wn);
        bool lt = d < d1[v];
        d2[v] = lt ? d1[v] : fminf(d2[v], d);
        d1[v] = lt ? d : d1[v];
        i1[v] = lt ? code : i1[v];
      }

    asm volatile("s_waitcnt vmcnt(0)" ::: "memory");
    __syncthreads();
  }

  // exact 2-min merge across the 16 code-columns (lanes sharing lq);
  // ascending chunk order + index tie-break == numpy first-min.
  #pragma unroll
  for (int m = 1; m < 16; m <<= 1) {
    #pragma unroll
    for (int v = 0; v < 8; ++v) {
      float od1 = __shfl_xor(d1[v], m, 64);
      float od2 = __shfl_xor(d2[v], m, 64);
      int   oi1 = __shfl_xor(i1[v], m, 64);
      d2[v] = fminf(fminf(d2[v], od2), fmaxf(d1[v], od1));
      bool take = (od1 < d1[v]) || (od1 == d1[v] && oi1 < i1[v]);
      d1[v] = take ? od1 : d1[v];
      i1[v] = take ? oi1 : i1[v];
    }
  }

  if (lr == 0) {                           // lanes 0,16,32,48 (lq = 0..3)
    #pragma unroll
    for (int tt = 0; tt < 2; ++tt)
      #pragma unroll
      for (int r = 0; r < 4; ++r) {
        int v = tt * 4 + r;
        int token = trow0 + tt * 16 + lq * 4 + r;
        cand[g * N_TOK + token] = d1[v];
        ((int*)cand)[CAND_I1 + g * N_TOK + token] = i1[v];
        cand[CAND_D2 + g * N_TOK + token] = d2[v];
      }
  }
}

// ---------------------------------------------------------------------------
// K1b: zero cluster-size accumulators. MUST run after k_argmin: B'' overlaps
// the CS region and is only dead once the GEMM has consumed it (R22 bug).
__global__ void k_zcs(float* __restrict__ out) {
  out[OFF_CS + blockIdx.x * 256 + threadIdx.x] = 0.f;
}

// ---------------------------------------------------------------------------
// K2: merge GROUPS candidates (exact 2-min); idx + margin flags.
// enc atomics deferred to k_enc (must use POST-refine idx).
__global__ void k_reduce(const float* __restrict__ cand, int* __restrict__ idx,
                         int* __restrict__ flags, int* __restrict__ fcnt) {
  int n = blockIdx.x * 256 + threadIdx.x;
  const int* ci = (const int*)cand + CAND_I1;
  float D1 = cand[n]; int I1 = ci[n]; float D2 = cand[CAND_D2 + n];
  #pragma unroll
  for (int g = 1; g < GROUPS; ++g) {
    float d = cand[g * N_TOK + n];
    int   i = ci[g * N_TOK + n];
    float dd = cand[CAND_D2 + g * N_TOK + n];
    D2 = fminf(fminf(D2, dd), fmaxf(D1, d));
    bool take = (d < D1) || (d == D1 && i < I1);
    D1 = take ? d : D1; I1 = take ? i : I1;
  }
  idx[n] = I1;
  if (D2 - D1 < MARGIN) {
    int p = atomicAdd(fcnt, 1);
    flags[p] = n;
  }
}

// ---------------------------------------------------------------------------
// K2b: exact fp32 argmin for flagged tokens.
__global__ void k_refine(const float* __restrict__ z, const float* __restrict__ weight,
                         const float* __restrict__ wnorm, const int* __restrict__ flags,
                         const int* __restrict__ fcnt, int* __restrict__ idx) {
  __shared__ float zt[EMB_D];
  __shared__ float rd[256];
  __shared__ int   ri[256];
  int cnt = *fcnt;
  for (int f = blockIdx.x; f < cnt; f += gridDim.x) {
    int n = flags[f];
    int b = n >> 10, hw = n & 1023;
    if (threadIdx.x < EMB_D) zt[threadIdx.x] = z[b * 65536 + threadIdx.x * 1024 + hw];
    __syncthreads();
    float bd = 3.4e38f; int bi = 0x7fffffff;
    for (int k = threadIdx.x; k < K_EMB; k += 256) {
      const float* wr = weight + k * EMB_D;
      float dot = 0.f;
      for (int d = 0; d < EMB_D; ++d) dot = fmaf(zt[d], wr[d], dot);
      float dist = fmaf(-2.f, dot, wnorm[k]);
      if (dist < bd || (dist == bd && k < bi)) { bd = dist; bi = k; }
    }
    rd[threadIdx.x] = bd; ri[threadIdx.x] = bi;
    __syncthreads();
    for (int s2 = 128; s2 > 0; s2 >>= 1) {
      if (threadIdx.x < s2) {
        float od = rd[threadIdx.x + s2]; int oi = ri[threadIdx.x + s2];
        if (od < rd[threadIdx.x] || (od == rd[threadIdx.x] && oi < ri[threadIdx.x])) {
          rd[threadIdx.x] = od; ri[threadIdx.x] = oi;
        }
      }
      __syncthreads();
    }
    if (threadIdx.x == 0) idx[n] = ri[0];
    __syncthreads();
  }
}

// ---------------------------------------------------------------------------
// K2c: enc counts from FINAL idx (CS zeroed by k_zcs).
__global__ void k_enc(const int* __restrict__ idx, float* __restrict__ enc) {
  int n = blockIdx.x * 256 + threadIdx.x;
  atomicAdd(enc + idx[n], 1.0f);
}

// ---------------------------------------------------------------------------
// K2d: zero embed-avg accumulators (cand lived here; cand is dead now).
// EA base is only 4B-aligned -> scalar stores.
__global__ void k_zea(float* __restrict__ out) {
  int base = OFF_EA + blockIdx.x * 1024;
  #pragma unroll
  for (int j = 0; j < 4; ++j) out[base + j * 256 + threadIdx.x] = 0.f;
}

// ---------------------------------------------------------------------------
// K3: z_q gather + straight-through output + loss partials + embed_sum atomics.
__global__ void k_quant(const float* __restrict__ z, const float* __restrict__ weight,
                        const int* __restrict__ idx, float* __restrict__ out,
                        float* __restrict__ embed_acc, float* __restrict__ ws) {
  int base = blockIdx.x * 1024 + threadIdx.x;
  float lsum = 0.f;
  #pragma unroll
  for (int i = 0; i < 4; ++i) {
    int e = base + i * 256;               // (b,c,hw) flat, same layout as z
    int c = (e >> 10) & 63;
    int n = ((e >> 16) << 10) | (e & 1023);
    int k = idx[n];
    float zv = z[e];
    float q = weight[k * EMB_D + c];
    out[e] = zv + (q - zv);               // straight-through value
    float d = q - zv;
    lsum += d * d;
    atomicAdd(embed_acc + k * EMB_D + c, zv);
  }
  #pragma unroll
  for (int off = 32; off > 0; off >>= 1) lsum += __shfl_xor(lsum, off, 64);
  __shared__ float red[4];
  int lane = threadIdx.x & 63, wv = threadIdx.x >> 6;
  if (lane == 0) red[wv] = lsum;
  __syncthreads();
  if (threadIdx.x == 0)
    atomicAdd(ws + WS_LOSS, red[0] + red[1] + red[2] + red[3]);
}

// ---------------------------------------------------------------------------
// K4: new_cluster_size (in place over enc_sum), n-sum, loss finalize.
__global__ void k_cluster(const float* __restrict__ cluster_in,
                          float* __restrict__ out, float* __restrict__ ws) {
  int k = blockIdx.x * 256 + threadIdx.x;
  float ncs = cluster_in[k] * 0.99f + 0.01f * out[OFF_CS + k];
  out[OFF_CS + k] = ncs;
  float s = ncs;
  #pragma unroll
  for (int off = 32; off > 0; off >>= 1) s += __shfl_xor(s, off, 64);
  __shared__ float red[4];
  int lane = threadIdx.x & 63, wv = threadIdx.x >> 6;
  if (lane == 0) red[wv] = s;
  __syncthreads();
  if (threadIdx.x == 0) atomicAdd(ws + WS_NSUM, red[0] + red[1] + red[2] + red[3]);
  if (blockIdx.x == 0 && threadIdx.x == 0)
    out[OFF_LOSS] = 0.25f * ws[WS_LOSS] * (1.0f / 1048576.0f);
}

// ---------------------------------------------------------------------------
// K5: smoothed cluster sizes -> new_weight; new_embed_avg (in place).
__global__ void k_final(const float* __restrict__ embed_avg,
                        float* __restrict__ out, const float* __restrict__ ws) {
  int e = blockIdx.x * 256 + threadIdx.x;   // < 524288
  int k = e >> 6;
  float ncs = out[OFF_CS + k];
  float nsum = ws[WS_NSUM];
  float sm = (ncs + 1e-5f) / (nsum + K_EMB * 1e-5f) * nsum;
  float ea = embed_avg[e] * 0.99f + 0.01f * out[OFF_EA + e];
  out[OFF_EA + e] = ea;
  out[OFF_W + e] = ea / sm;
}

// ---------------------------------------------------------------------------
extern "C" void kernel_launch(void* const* d_in, const int* in_sizes, int n_in,
                              void* d_out, int out_size, void* d_ws, size_t ws_size,
                              hipStream_t stream) {
  const float* z = (const float*)d_in[0];
  const float* weight = (const float*)d_in[1];
  const float* cluster = (const float*)d_in[2];
  const float* embed_avg = (const float*)d_in[3];
  float* out = (float*)d_out;
  float* ws = (float*)d_ws;
  float* wnorm = ws + WS_WNORM;
  int* idx = (int*)(ws + WS_IDX);
  int* fcnt = (int*)ws + WS_FCNT;
  const short* Ap = (const short*)out;                     // A' in z_q region
  const short* Bp = (const short*)((unsigned short*)out + B_BASE);
  float* cand = out + OFF_EA;
  int* flags = (int*)out;                                  // z_q region ints

  hipLaunchKernelGGL(k_prep, dim3(512), dim3(256), 0, stream, weight, out, ws);
  hipLaunchKernelGGL(k_prep_a, dim3(64), dim3(256), 0, stream, z, out);
  hipLaunchKernelGGL(k_argmin, dim3(1024), dim3(256), 0, stream,
                     Ap, Bp, wnorm, cand);
  hipLaunchKernelGGL(k_zcs, dim3(K_EMB / 256), dim3(256), 0, stream, out);
  hipLaunchKernelGGL(k_reduce, dim3(N_TOK / 256), dim3(256), 0, stream,
                     cand, idx, flags, fcnt);
  hipLaunchKernelGGL(k_refine, dim3(64), dim3(256), 0, stream,
                     z, weight, wnorm, flags, fcnt, idx);
  hipLaunchKernelGGL(k_enc, dim3(N_TOK / 256), dim3(256), 0, stream,
                     idx, out + OFF_CS);
  hipLaunchKernelGGL(k_zea, dim3(512), dim3(256), 0, stream, out);
  hipLaunchKernelGGL(k_quant, dim3(1024), dim3(256), 0, stream,
                     z, weight, idx, out, out + OFF_EA, ws);
  hipLaunchKernelGGL(k_cluster, dim3(K_EMB / 256), dim3(256), 0, stream,
                     cluster, out, ws);
  hipLaunchKernelGGL(k_final, dim3(524288 / 256), dim3(256), 0, stream,
                     embed_avg, out, ws);
}

// Round 7
// 334.651 us; speedup vs baseline: 1.8350x; 1.1821x over previous
//
#include <hip/hip_runtime.h>

// EMA Vector-Quantizer for MI355X (gfx950).
// N=16384 tokens, D=64, K=8192.
// R17-R19: fp32 VALU distance GEMM plateau 203us (no fp32 MFMA on CDNA4).
// R20-R23: bf16 hi/lo split GEMM on the matrix pipe (dot = (zh+zl).(wh+wl),
// 8 MFMAs incl cross terms; exact 2nd-best margin + fp32 refine safety net).
// R23 passed 395us; top dispatch is now k_refine @ 135us (occupancy 2.7%,
// VALU 1.5%: one token per block, uncoalesced 256B-strided row reads,
// serial 64-deep fma chains -> latency-bound crawl over a 2MB table).
// R24 (this): refine rewritten as wave-per-code:
//  - work item = (flagged token f, 1024-code subrange s); fixed 1024-block
//    grid loops w < cnt*8 -> parallelism scales with flag count.
//  - lane d holds z_d; per code: coalesced 256B row load + butterfly
//    __shfl_xor reduce = exact fp32 dot (deterministic order).
//  - cross-block merge: atomicMin on packed u64 (monotone-float(dist)<<32 |
//    k) -> min dist then min k == numpy first-min. k_unpack writes idx.
//  - packed[16384] u64 lives in EA free tail (PK_BASE even float idx ->
//    8B aligned; dead before k_zea zeroes EA).
// Predicted: k_refine 135 -> <10us, total ~260-285us, top dispatch k_argmin.

#define N_TOK 16384
#define K_EMB 8192
#define EMB_D 64
#define GROUPS 8

typedef short bf8 __attribute__((ext_vector_type(8)));
typedef float f32x4 __attribute__((ext_vector_type(4)));
typedef unsigned short us4 __attribute__((ext_vector_type(4)));

// d_out flat layout (float32), reference return order:
// z_q (1048576) | loss | new_weight (524288) | new_cluster_size (8192) | new_embed_avg (524288)
#define OFF_LOSS 1048576
#define OFF_W    1048577
#define OFF_CS   1572865
#define OFF_EA   1581057

// scratch offsets
#define B_BASE   2113536   // ushort index into out = byte 4227072 (16B aligned)
                           // B'' = 2MB = floats [1056768, 1581056): W tail + CS.
                           // CS re-zeroed by k_zcs AFTER k_argmin (R22 lesson).
#define CAND_I1  131072    // within EA-based cand area (floats/ints)
#define CAND_D2  262144
#define PK_BASE  (OFF_EA + 393217)  // even float idx -> 8B-aligned u64[16384]

#define MARGIN 0.03f

// ws float offsets
#define WS_NSUM  0
#define WS_LOSS  1
#define WS_FCNT  2        // int
#define WS_WNORM 16
#define WS_IDX   (WS_WNORM + K_EMB)

__device__ __forceinline__ unsigned short f2bf(float x) {
  unsigned int b = __float_as_uint(x);
  return (unsigned short)((b + 0x7fff + ((b >> 16) & 1)) >> 16);
}
__device__ __forceinline__ float bf2f(unsigned short h) {
  return __uint_as_float(((unsigned int)h) << 16);
}

// async global->LDS, 16B per lane (dest = wave-uniform base + lane*16)
__device__ __forceinline__ void gload16(const void* g, void* l) {
  __builtin_amdgcn_global_load_lds(
      (const __attribute__((address_space(1))) void*)g,
      (__attribute__((address_space(3))) void*)l, 16, 0, 0);
}

// ---------------------------------------------------------------------------
// K0: wnorm[k]; B'' chunk layout [chunk][seg][lq][code] (shorts); ws scalars.
// Chunk = 16 codes = 2048 shorts; seg s (0..3) = [wh k0-31|wh k32-63|
// wl k0-31|wl k32-63]; within seg: lq (k%32/8) * 128 + code*8 + k%8.
__global__ void k_prep(const float* __restrict__ weight,
                       float* __restrict__ out, float* __restrict__ ws) {
  int gid = blockIdx.x * 256 + threadIdx.x;     // 0..131071
  int row = gid >> 4;                            // codebook row 0..8191
  int l16 = gid & 15;
  float4 w4 = *(const float4*)(weight + row * EMB_D + l16 * 4);
  float s = w4.x * w4.x + w4.y * w4.y + w4.z * w4.z + w4.w * w4.w;
  #pragma unroll
  for (int off = 8; off > 0; off >>= 1) s += __shfl_xor(s, off, 16);
  if (l16 == 0) ws[WS_WNORM + row] = s;

  float wv[4] = {w4.x, w4.y, w4.z, w4.w};
  us4 hi, lo;
  #pragma unroll
  for (int e = 0; e < 4; ++e) {
    unsigned short h = f2bf(wv[e]);
    hi[e] = h;
    lo[e] = f2bf(wv[e] - bf2f(h));
  }
  // d0..d0+3 land in seg sp (hi) / 2+sp (lo), slot lqp, j = jj..jj+3
  int d0 = l16 * 4;
  int jj = d0 & 7;                 // 0 or 4
  int lqp = (d0 >> 3) & 3;
  int sp = d0 >> 5;                // 0 or 1
  unsigned short* bp = (unsigned short*)out + B_BASE
      + (row >> 4) * 2048 + (row & 15) * 8 + lqp * 128 + jj;
  *(us4*)(bp + sp * 512) = hi;
  *(us4*)(bp + (2 + sp) * 512) = lo;

  if (gid == 0) {
    out[OFF_LOSS] = 0.f; ws[WS_NSUM] = 0.f; ws[WS_LOSS] = 0.f;
    ((int*)ws)[WS_FCNT] = 0;
  }
}

// ---------------------------------------------------------------------------
// K0b: A' = [bf16_hi | bf16_lo] per token row, via LDS transpose.
// z is (b,c,hw): z_flat[n][d] = z[b*65536 + d*1024 + hw], n = b*1024+hw.
__global__ void k_prep_a(const float* __restrict__ z, float* __restrict__ out) {
  __shared__ float z_s[EMB_D * 256];
  const int t = threadIdx.x;
  const int b = blockIdx.x >> 2;
  const int hw0 = (blockIdx.x & 3) * 256;
  const float* zb = z + b * 65536 + hw0;
  #pragma unroll
  for (int i = 0; i < 16; ++i) {
    int f4 = i * 256 + t;
    int d = f4 >> 6, c4 = (f4 & 63) * 4;
    *(float4*)(z_s + d * 256 + c4) = *(const float4*)(zb + d * 1024 + c4);
  }
  __syncthreads();
  int tok = b * 1024 + hw0 + t;
  unsigned short* ap = (unsigned short*)out + tok * 128;
  #pragma unroll
  for (int j = 0; j < 16; ++j) {          // 16 groups of 4 d-values
    us4 hi, lo;
    #pragma unroll
    for (int e = 0; e < 4; ++e) {
      float zv = z_s[(j * 4 + e) * 256 + t];
      unsigned short h = f2bf(zv);
      hi[e] = h;
      lo[e] = f2bf(zv - bf2f(h));
    }
    *(us4*)(ap + j * 4) = hi;
    *(us4*)(ap + 64 + j * 4) = lo;
  }
}

// ---------------------------------------------------------------------------
// K1: distance argmin on the matrix pipe, LDS-staged B, spill-proof tiling.
// Grid 1024 blocks 1-D; g = bid&7 (XCD swizzle: one k-group per XCD),
// tok_blk = bid>>3. Block = 4 waves x 32 tokens = 128 tokens, scanning all
// 1024 codes of group g in 64 chunks of 16. Per chunk: 1 gload16/thread
// stages next 4KB; 4 conflict-free ds_read_b128 b-frags; 16 MFMAs
// (2 token-tiles x (4 direct + 4 cross)); exact (d1,i1,d2) update.
// C layout: col=lane&15 (code), row=(lane>>4)*4+reg (token) [m89-verified].
__global__ __launch_bounds__(256, 4) void k_argmin(
    const short* __restrict__ A, const short* __restrict__ B,
    const float* __restrict__ wnorm, float* __restrict__ cand) {
  __shared__ __align__(16) short wbuf[2][2048];   // 2 x 4KB chunk dbuf
  __shared__ __align__(16) float wn_s[1024];      // group wnorm
  const int t = threadIdx.x;
  const int lane = t & 63;
  const int wid = __builtin_amdgcn_readfirstlane(t >> 6);  // 0..3
  const int g = blockIdx.x & 7;
  const int tok_blk = blockIdx.x >> 3;
  const int trow0 = tok_blk * 128 + wid * 32;
  const int lr = lane & 15, lq = lane >> 4;

  // A-frags: 2 token-tiles x 4 k-segs (zh k0-31, zh k32-63, zl k0-31, zl k32-63)
  bf8 a[2][4];
  #pragma unroll
  for (int tt = 0; tt < 2; ++tt) {
    const short* ap = A + (size_t)(trow0 + tt * 16 + lr) * 128 + lq * 8;
    #pragma unroll
    for (int s = 0; s < 4; ++s) a[tt][s] = *(const bf8*)(ap + s * 32);
  }

  const short* bsrc = B + (size_t)g * 64 * 2048;  // group panel: 64 chunks

  // stage wnorm (4KB) + chunk 0
  *(float4*)(wn_s + t * 4) = *(const float4*)(wnorm + g * 1024 + t * 4);
  gload16(bsrc + t * 8, &wbuf[0][0] + t * 8);
  asm volatile("s_waitcnt vmcnt(0)" ::: "memory");
  __syncthreads();

  float d1[8], d2[8]; int i1[8];
  #pragma unroll
  for (int v = 0; v < 8; ++v) { d1[v] = 3.4e38f; d2[v] = 3.4e38f; i1[v] = 0; }

  for (int c = 0; c < 64; ++c) {
    if (c + 1 < 64)
      gload16(bsrc + (c + 1) * 2048 + t * 8, &wbuf[(c + 1) & 1][0] + t * 8);

    const short* cb = &wbuf[c & 1][0];
    bf8 bfr[4];
    #pragma unroll
    for (int s = 0; s < 4; ++s)
      bfr[s] = *(const bf8*)(cb + s * 512 + lq * 128 + lr * 8);
    float wn = wn_s[c * 16 + lr];

    f32x4 acc[2];
    acc[0] = (f32x4)(0.f); acc[1] = (f32x4)(0.f);
    #pragma unroll
    for (int tt = 0; tt < 2; ++tt) {
      // direct: zh.wh + zl.wl
      acc[tt] = __builtin_amdgcn_mfma_f32_16x16x32_bf16(a[tt][0], bfr[0], acc[tt], 0, 0, 0);
      acc[tt] = __builtin_amdgcn_mfma_f32_16x16x32_bf16(a[tt][1], bfr[1], acc[tt], 0, 0, 0);
      acc[tt] = __builtin_amdgcn_mfma_f32_16x16x32_bf16(a[tt][2], bfr[2], acc[tt], 0, 0, 0);
      acc[tt] = __builtin_amdgcn_mfma_f32_16x16x32_bf16(a[tt][3], bfr[3], acc[tt], 0, 0, 0);
      // cross: zh.wl + zl.wh  -> total = (zh+zl).(wh+wl)
      acc[tt] = __builtin_amdgcn_mfma_f32_16x16x32_bf16(a[tt][0], bfr[2], acc[tt], 0, 0, 0);
      acc[tt] = __builtin_amdgcn_mfma_f32_16x16x32_bf16(a[tt][1], bfr[3], acc[tt], 0, 0, 0);
      acc[tt] = __builtin_amdgcn_mfma_f32_16x16x32_bf16(a[tt][2], bfr[0], acc[tt], 0, 0, 0);
      acc[tt] = __builtin_amdgcn_mfma_f32_16x16x32_bf16(a[tt][3], bfr[1], acc[tt], 0, 0, 0);
    }

    const int code = g * 1024 + c * 16 + lr;
    #pragma unroll
    for (int tt = 0; tt < 2; ++tt)
      #pragma unroll
      for (int r = 0; r < 4; ++r) {
        const int v = tt * 4 + r;
        float d = fmaf(-2.f, acc[tt][r], wn);
        bool lt = d < d1[v];
        d2[v] = lt ? d1[v] : fminf(d2[v], d);
        d1[v] = lt ? d : d1[v];
        i1[v] = lt ? code : i1[v];
      }

    asm volatile("s_waitcnt vmcnt(0)" ::: "memory");
    __syncthreads();
  }

  // exact 2-min merge across the 16 code-columns (lanes sharing lq);
  // ascending chunk order + index tie-break == numpy first-min.
  #pragma unroll
  for (int m = 1; m < 16; m <<= 1) {
    #pragma unroll
    for (int v = 0; v < 8; ++v) {
      float od1 = __shfl_xor(d1[v], m, 64);
      float od2 = __shfl_xor(d2[v], m, 64);
      int   oi1 = __shfl_xor(i1[v], m, 64);
      d2[v] = fminf(fminf(d2[v], od2), fmaxf(d1[v], od1));
      bool take = (od1 < d1[v]) || (od1 == d1[v] && oi1 < i1[v]);
      d1[v] = take ? od1 : d1[v];
      i1[v] = take ? oi1 : i1[v];
    }
  }

  if (lr == 0) {                           // lanes 0,16,32,48 (lq = 0..3)
    #pragma unroll
    for (int tt = 0; tt < 2; ++tt)
      #pragma unroll
      for (int r = 0; r < 4; ++r) {
        int v = tt * 4 + r;
        int token = trow0 + tt * 16 + lq * 4 + r;
        cand[g * N_TOK + token] = d1[v];
        ((int*)cand)[CAND_I1 + g * N_TOK + token] = i1[v];
        cand[CAND_D2 + g * N_TOK + token] = d2[v];
      }
  }
}

// ---------------------------------------------------------------------------
// K1b: zero cluster-size accumulators. MUST run after k_argmin: B'' overlaps
// the CS region and is only dead once the GEMM has consumed it (R22 bug).
__global__ void k_zcs(float* __restrict__ out) {
  out[OFF_CS + blockIdx.x * 256 + threadIdx.x] = 0.f;
}

// ---------------------------------------------------------------------------
// K2: merge GROUPS candidates (exact 2-min); idx + margin flags; init packed
// slot for flagged tokens. enc atomics deferred to k_enc (POST-refine idx).
__global__ void k_reduce(const float* __restrict__ cand, int* __restrict__ idx,
                         int* __restrict__ flags, int* __restrict__ fcnt,
                         unsigned long long* __restrict__ packed) {
  int n = blockIdx.x * 256 + threadIdx.x;
  const int* ci = (const int*)cand + CAND_I1;
  float D1 = cand[n]; int I1 = ci[n]; float D2 = cand[CAND_D2 + n];
  #pragma unroll
  for (int g = 1; g < GROUPS; ++g) {
    float d = cand[g * N_TOK + n];
    int   i = ci[g * N_TOK + n];
    float dd = cand[CAND_D2 + g * N_TOK + n];
    D2 = fminf(fminf(D2, dd), fmaxf(D1, d));
    bool take = (d < D1) || (d == D1 && i < I1);
    D1 = take ? d : D1; I1 = take ? i : I1;
  }
  idx[n] = I1;
  if (D2 - D1 < MARGIN) {
    packed[n] = ~0ull;
    int p = atomicAdd(fcnt, 1);
    flags[p] = n;
  }
}

// ---------------------------------------------------------------------------
// K2b: exact fp32 refine, wave-per-code. Work item w = (f, sub): token
// flags[f], codes [sub*1024, +1024). Wave wv handles 256 codes; lane d
// holds z_d; per code: coalesced 256B row load + butterfly reduce (exact,
// deterministic). Merge via atomicMin on packed (monotone(dist)<<32 | k):
// min dist, then min k == numpy first-min.
__global__ void k_refine(const float* __restrict__ z, const float* __restrict__ weight,
                         const float* __restrict__ wnorm, const int* __restrict__ flags,
                         const int* __restrict__ fcnt,
                         unsigned long long* __restrict__ packed) {
  const int cnt = *fcnt;
  const int lane = threadIdx.x & 63;
  const int wv = threadIdx.x >> 6;
  for (int w = blockIdx.x; w < cnt * 8; w += gridDim.x) {
    const int f = w >> 3, sub = w & 7;
    const int n = flags[f];
    const int b = n >> 10, hw = n & 1023;
    const float zd = z[b * 65536 + lane * 1024 + hw];   // lane holds z[d=lane]
    float bd = 3.4e38f; int bi = 0;
    const int k0 = sub * 1024 + wv * 256;
    #pragma unroll 4
    for (int i = 0; i < 256; ++i) {
      const int k = k0 + i;
      float prod = zd * weight[k * EMB_D + lane];
      #pragma unroll
      for (int off = 32; off > 0; off >>= 1) prod += __shfl_xor(prod, off, 64);
      float dist = fmaf(-2.f, prod, wnorm[k]);
      if (dist < bd) { bd = dist; bi = k; }   // ascending k: strict < = first-min
    }
    if (lane == 0) {
      unsigned int bits = __float_as_uint(bd);
      unsigned int u = (bits & 0x80000000u) ? ~bits : (bits | 0x80000000u);
      atomicMin(packed + n, ((unsigned long long)u << 32) | (unsigned int)bi);
    }
  }
}

// ---------------------------------------------------------------------------
// K2b2: unpack refined winners into idx (flagged tokens only).
__global__ void k_unpack(const unsigned long long* __restrict__ packed,
                         const int* __restrict__ flags, const int* __restrict__ fcnt,
                         int* __restrict__ idx) {
  int i = blockIdx.x * 256 + threadIdx.x;
  if (i < *fcnt) {
    int n = flags[i];
    idx[n] = (int)(packed[n] & 0xffffffffull);
  }
}

// ---------------------------------------------------------------------------
// K2c: enc counts from FINAL idx (CS zeroed by k_zcs).
__global__ void k_enc(const int* __restrict__ idx, float* __restrict__ enc) {
  int n = blockIdx.x * 256 + threadIdx.x;
  atomicAdd(enc + idx[n], 1.0f);
}

// ---------------------------------------------------------------------------
// K2d: zero embed-avg accumulators (cand + packed lived here; dead now).
// EA base is only 4B-aligned -> scalar stores.
__global__ void k_zea(float* __restrict__ out) {
  int base = OFF_EA + blockIdx.x * 1024;
  #pragma unroll
  for (int j = 0; j < 4; ++j) out[base + j * 256 + threadIdx.x] = 0.f;
}

// ---------------------------------------------------------------------------
// K3: z_q gather + straight-through output + loss partials + embed_sum atomics.
__global__ void k_quant(const float* __restrict__ z, const float* __restrict__ weight,
                        const int* __restrict__ idx, float* __restrict__ out,
                        float* __restrict__ embed_acc, float* __restrict__ ws) {
  int base = blockIdx.x * 1024 + threadIdx.x;
  float lsum = 0.f;
  #pragma unroll
  for (int i = 0; i < 4; ++i) {
    int e = base + i * 256;               // (b,c,hw) flat, same layout as z
    int c = (e >> 10) & 63;
    int n = ((e >> 16) << 10) | (e & 1023);
    int k = idx[n];
    float zv = z[e];
    float q = weight[k * EMB_D + c];
    out[e] = zv + (q - zv);               // straight-through value
    float d = q - zv;
    lsum += d * d;
    atomicAdd(embed_acc + k * EMB_D + c, zv);
  }
  #pragma unroll
  for (int off = 32; off > 0; off >>= 1) lsum += __shfl_xor(lsum, off, 64);
  __shared__ float red[4];
  int lane = threadIdx.x & 63, wv = threadIdx.x >> 6;
  if (lane == 0) red[wv] = lsum;
  __syncthreads();
  if (threadIdx.x == 0)
    atomicAdd(ws + WS_LOSS, red[0] + red[1] + red[2] + red[3]);
}

// ---------------------------------------------------------------------------
// K4: new_cluster_size (in place over enc_sum), n-sum, loss finalize.
__global__ void k_cluster(const float* __restrict__ cluster_in,
                          float* __restrict__ out, float* __restrict__ ws) {
  int k = blockIdx.x * 256 + threadIdx.x;
  float ncs = cluster_in[k] * 0.99f + 0.01f * out[OFF_CS + k];
  out[OFF_CS + k] = ncs;
  float s = ncs;
  #pragma unroll
  for (int off = 32; off > 0; off >>= 1) s += __shfl_xor(s, off, 64);
  __shared__ float red[4];
  int lane = threadIdx.x & 63, wv = threadIdx.x >> 6;
  if (lane == 0) red[wv] = s;
  __syncthreads();
  if (threadIdx.x == 0) atomicAdd(ws + WS_NSUM, red[0] + red[1] + red[2] + red[3]);
  if (blockIdx.x == 0 && threadIdx.x == 0)
    out[OFF_LOSS] = 0.25f * ws[WS_LOSS] * (1.0f / 1048576.0f);
}

// ---------------------------------------------------------------------------
// K5: smoothed cluster sizes -> new_weight; new_embed_avg (in place).
__global__ void k_final(const float* __restrict__ embed_avg,
                        float* __restrict__ out, const float* __restrict__ ws) {
  int e = blockIdx.x * 256 + threadIdx.x;   // < 524288
  int k = e >> 6;
  float ncs = out[OFF_CS + k];
  float nsum = ws[WS_NSUM];
  float sm = (ncs + 1e-5f) / (nsum + K_EMB * 1e-5f) * nsum;
  float ea = embed_avg[e] * 0.99f + 0.01f * out[OFF_EA + e];
  out[OFF_EA + e] = ea;
  out[OFF_W + e] = ea / sm;
}

// ---------------------------------------------------------------------------
extern "C" void kernel_launch(void* const* d_in, const int* in_sizes, int n_in,
                              void* d_out, int out_size, void* d_ws, size_t ws_size,
                              hipStream_t stream) {
  const float* z = (const float*)d_in[0];
  const float* weight = (const float*)d_in[1];
  const float* cluster = (const float*)d_in[2];
  const float* embed_avg = (const float*)d_in[3];
  float* out = (float*)d_out;
  float* ws = (float*)d_ws;
  float* wnorm = ws + WS_WNORM;
  int* idx = (int*)(ws + WS_IDX);
  int* fcnt = (int*)ws + WS_FCNT;
  const short* Ap = (const short*)out;                     // A' in z_q region
  const short* Bp = (const short*)((unsigned short*)out + B_BASE);
  float* cand = out + OFF_EA;
  int* flags = (int*)out;                                  // z_q region ints
  unsigned long long* packed = (unsigned long long*)(out + PK_BASE);

  hipLaunchKernelGGL(k_prep, dim3(512), dim3(256), 0, stream, weight, out, ws);
  hipLaunchKernelGGL(k_prep_a, dim3(64), dim3(256), 0, stream, z, out);
  hipLaunchKernelGGL(k_argmin, dim3(1024), dim3(256), 0, stream,
                     Ap, Bp, wnorm, cand);
  hipLaunchKernelGGL(k_zcs, dim3(K_EMB / 256), dim3(256), 0, stream, out);
  hipLaunchKernelGGL(k_reduce, dim3(N_TOK / 256), dim3(256), 0, stream,
                     cand, idx, flags, fcnt, packed);
  hipLaunchKernelGGL(k_refine, dim3(1024), dim3(256), 0, stream,
                     z, weight, wnorm, flags, fcnt, packed);
  hipLaunchKernelGGL(k_unpack, dim3(N_TOK / 256), dim3(256), 0, stream,
                     packed, flags, fcnt, idx);
  hipLaunchKernelGGL(k_enc, dim3(N_TOK / 256), dim3(256), 0, stream,
                     idx, out + OFF_CS);
  hipLaunchKernelGGL(k_zea, dim3(512), dim3(256), 0, stream, out);
  hipLaunchKernelGGL(k_quant, dim3(1024), dim3(256), 0, stream,
                     z, weight, idx, out, out + OFF_EA, ws);
  hipLaunchKernelGGL(k_cluster, dim3(K_EMB / 256), dim3(256), 0, stream,
                     cluster, out, ws);
  hipLaunchKernelGGL(k_final, dim3(524288 / 256), dim3(256), 0, stream,
                     embed_avg, out, ws);
}

// Round 8
// 285.710 us; speedup vs baseline: 2.1493x; 1.1713x over previous
//
#include <hip/hip_runtime.h>

// EMA Vector-Quantizer for MI355X (gfx950).
// N=16384 tokens, D=64, K=8192.
// R17-R19: fp32 VALU distance GEMM plateau 203us (no fp32 MFMA on CDNA4).
// R20-R23: bf16 hi/lo split GEMM on matrix pipe + exact-margin fp32 refine.
// R24: wave-per-code refine (135->off top-5); 334us; k_quant now top @104us:
// 1M scattered fp32 atomicAdds into 2MB embed region -> atomic-RMW bound
// (VALU 0.6%, WRITE 36.9MB vs 6MB ideal, 10 Gatomic/s).
// R25 (this): embed_sum via counting-sort segment reduction, NO atomics:
//   k_scan (1 blk): exclusive prefix of k_enc counts -> offs + cursors.
//   k_scatter: tokenlist grouped by code (16K atomics on 8K cursors).
//   k_embed: wave per code; lane d sums zh+zl from token-major A' rows
//     (coalesced, exact to 2^-17|z|); writes embed[k][d] coalesced; fully
//     overwrites EA -> k_zea dropped. Runs BEFORE k_quant overwrites A'.
//   k_quant: z_q + loss only.
//   flags moved to dead-B'' scratch (k_embed now reads A' after k_reduce).
// Scratch liveness (out buffer):
//   A' bf16[16384][128] @ 0      : k_prep_a -> ... -> k_embed, then z_q
//   B'' @ float 1056768 (2MB)    : k_prep -> k_argmin, then int scratch
//     FLAGS@1056768 TOK@1073152 OFFS@1089536 CURS@1097736 (all < CS)
//   cand/packed in EA            : k_argmin -> k_unpack, then k_embed owns EA
//   CS counts: k_zcs(post-argmin) -> k_enc -> k_scan/k_cluster
// Predicted: k_quant 104 -> 10-15us, total ~240-265us, top = k_argmin.

#define N_TOK 16384
#define K_EMB 8192
#define EMB_D 64
#define GROUPS 8

typedef short bf8 __attribute__((ext_vector_type(8)));
typedef float f32x4 __attribute__((ext_vector_type(4)));
typedef unsigned short us4 __attribute__((ext_vector_type(4)));

// d_out flat layout (float32), reference return order:
// z_q (1048576) | loss | new_weight (524288) | new_cluster_size (8192) | new_embed_avg (524288)
#define OFF_LOSS 1048576
#define OFF_W    1048577
#define OFF_CS   1572865
#define OFF_EA   1581057

// scratch offsets
#define B_BASE   2113536   // ushort index into out = byte 4227072 (16B aligned)
#define CAND_I1  131072    // within EA-based cand area (floats/ints)
#define CAND_D2  262144
#define PK_BASE  (OFF_EA + 393217)  // even float idx -> 8B-aligned u64[16384]

// int-indexed scratch in dead-B'' (W region, consumed before k_final)
#define SCR_FLAGS 1056768
#define SCR_TOK   1073152
#define SCR_OFFS  1089536
#define SCR_CURS  1097736

#define MARGIN 0.03f

// ws float offsets
#define WS_NSUM  0
#define WS_LOSS  1
#define WS_FCNT  2        // int
#define WS_WNORM 16
#define WS_IDX   (WS_WNORM + K_EMB)

__device__ __forceinline__ unsigned short f2bf(float x) {
  unsigned int b = __float_as_uint(x);
  return (unsigned short)((b + 0x7fff + ((b >> 16) & 1)) >> 16);
}
__device__ __forceinline__ float bf2f(unsigned short h) {
  return __uint_as_float(((unsigned int)h) << 16);
}

// async global->LDS, 16B per lane (dest = wave-uniform base + lane*16)
__device__ __forceinline__ void gload16(const void* g, void* l) {
  __builtin_amdgcn_global_load_lds(
      (const __attribute__((address_space(1))) void*)g,
      (__attribute__((address_space(3))) void*)l, 16, 0, 0);
}

// ---------------------------------------------------------------------------
// K0: wnorm[k]; B'' chunk layout [chunk][seg][lq][code] (shorts); ws scalars.
__global__ void k_prep(const float* __restrict__ weight,
                       float* __restrict__ out, float* __restrict__ ws) {
  int gid = blockIdx.x * 256 + threadIdx.x;     // 0..131071
  int row = gid >> 4;                            // codebook row 0..8191
  int l16 = gid & 15;
  float4 w4 = *(const float4*)(weight + row * EMB_D + l16 * 4);
  float s = w4.x * w4.x + w4.y * w4.y + w4.z * w4.z + w4.w * w4.w;
  #pragma unroll
  for (int off = 8; off > 0; off >>= 1) s += __shfl_xor(s, off, 16);
  if (l16 == 0) ws[WS_WNORM + row] = s;

  float wv[4] = {w4.x, w4.y, w4.z, w4.w};
  us4 hi, lo;
  #pragma unroll
  for (int e = 0; e < 4; ++e) {
    unsigned short h = f2bf(wv[e]);
    hi[e] = h;
    lo[e] = f2bf(wv[e] - bf2f(h));
  }
  int d0 = l16 * 4;
  int jj = d0 & 7;                 // 0 or 4
  int lqp = (d0 >> 3) & 3;
  int sp = d0 >> 5;                // 0 or 1
  unsigned short* bp = (unsigned short*)out + B_BASE
      + (row >> 4) * 2048 + (row & 15) * 8 + lqp * 128 + jj;
  *(us4*)(bp + sp * 512) = hi;
  *(us4*)(bp + (2 + sp) * 512) = lo;

  if (gid == 0) {
    out[OFF_LOSS] = 0.f; ws[WS_NSUM] = 0.f; ws[WS_LOSS] = 0.f;
    ((int*)ws)[WS_FCNT] = 0;
  }
}

// ---------------------------------------------------------------------------
// K0b: A' = [bf16_hi | bf16_lo] per token row, via LDS transpose.
__global__ void k_prep_a(const float* __restrict__ z, float* __restrict__ out) {
  __shared__ float z_s[EMB_D * 256];
  const int t = threadIdx.x;
  const int b = blockIdx.x >> 2;
  const int hw0 = (blockIdx.x & 3) * 256;
  const float* zb = z + b * 65536 + hw0;
  #pragma unroll
  for (int i = 0; i < 16; ++i) {
    int f4 = i * 256 + t;
    int d = f4 >> 6, c4 = (f4 & 63) * 4;
    *(float4*)(z_s + d * 256 + c4) = *(const float4*)(zb + d * 1024 + c4);
  }
  __syncthreads();
  int tok = b * 1024 + hw0 + t;
  unsigned short* ap = (unsigned short*)out + tok * 128;
  #pragma unroll
  for (int j = 0; j < 16; ++j) {
    us4 hi, lo;
    #pragma unroll
    for (int e = 0; e < 4; ++e) {
      float zv = z_s[(j * 4 + e) * 256 + t];
      unsigned short h = f2bf(zv);
      hi[e] = h;
      lo[e] = f2bf(zv - bf2f(h));
    }
    *(us4*)(ap + j * 4) = hi;
    *(us4*)(ap + 64 + j * 4) = lo;
  }
}

// ---------------------------------------------------------------------------
// K1: distance argmin on the matrix pipe, LDS-staged B, spill-proof tiling.
// (unchanged from R23; see header)
__global__ __launch_bounds__(256, 4) void k_argmin(
    const short* __restrict__ A, const short* __restrict__ B,
    const float* __restrict__ wnorm, float* __restrict__ cand) {
  __shared__ __align__(16) short wbuf[2][2048];   // 2 x 4KB chunk dbuf
  __shared__ __align__(16) float wn_s[1024];      // group wnorm
  const int t = threadIdx.x;
  const int lane = t & 63;
  const int wid = __builtin_amdgcn_readfirstlane(t >> 6);  // 0..3
  const int g = blockIdx.x & 7;
  const int tok_blk = blockIdx.x >> 3;
  const int trow0 = tok_blk * 128 + wid * 32;
  const int lr = lane & 15, lq = lane >> 4;

  bf8 a[2][4];
  #pragma unroll
  for (int tt = 0; tt < 2; ++tt) {
    const short* ap = A + (size_t)(trow0 + tt * 16 + lr) * 128 + lq * 8;
    #pragma unroll
    for (int s = 0; s < 4; ++s) a[tt][s] = *(const bf8*)(ap + s * 32);
  }

  const short* bsrc = B + (size_t)g * 64 * 2048;

  *(float4*)(wn_s + t * 4) = *(const float4*)(wnorm + g * 1024 + t * 4);
  gload16(bsrc + t * 8, &wbuf[0][0] + t * 8);
  asm volatile("s_waitcnt vmcnt(0)" ::: "memory");
  __syncthreads();

  float d1[8], d2[8]; int i1[8];
  #pragma unroll
  for (int v = 0; v < 8; ++v) { d1[v] = 3.4e38f; d2[v] = 3.4e38f; i1[v] = 0; }

  for (int c = 0; c < 64; ++c) {
    if (c + 1 < 64)
      gload16(bsrc + (c + 1) * 2048 + t * 8, &wbuf[(c + 1) & 1][0] + t * 8);

    const short* cb = &wbuf[c & 1][0];
    bf8 bfr[4];
    #pragma unroll
    for (int s = 0; s < 4; ++s)
      bfr[s] = *(const bf8*)(cb + s * 512 + lq * 128 + lr * 8);
    float wn = wn_s[c * 16 + lr];

    f32x4 acc[2];
    acc[0] = (f32x4)(0.f); acc[1] = (f32x4)(0.f);
    #pragma unroll
    for (int tt = 0; tt < 2; ++tt) {
      acc[tt] = __builtin_amdgcn_mfma_f32_16x16x32_bf16(a[tt][0], bfr[0], acc[tt], 0, 0, 0);
      acc[tt] = __builtin_amdgcn_mfma_f32_16x16x32_bf16(a[tt][1], bfr[1], acc[tt], 0, 0, 0);
      acc[tt] = __builtin_amdgcn_mfma_f32_16x16x32_bf16(a[tt][2], bfr[2], acc[tt], 0, 0, 0);
      acc[tt] = __builtin_amdgcn_mfma_f32_16x16x32_bf16(a[tt][3], bfr[3], acc[tt], 0, 0, 0);
      acc[tt] = __builtin_amdgcn_mfma_f32_16x16x32_bf16(a[tt][0], bfr[2], acc[tt], 0, 0, 0);
      acc[tt] = __builtin_amdgcn_mfma_f32_16x16x32_bf16(a[tt][1], bfr[3], acc[tt], 0, 0, 0);
      acc[tt] = __builtin_amdgcn_mfma_f32_16x16x32_bf16(a[tt][2], bfr[0], acc[tt], 0, 0, 0);
      acc[tt] = __builtin_amdgcn_mfma_f32_16x16x32_bf16(a[tt][3], bfr[1], acc[tt], 0, 0, 0);
    }

    const int code = g * 1024 + c * 16 + lr;
    #pragma unroll
    for (int tt = 0; tt < 2; ++tt)
      #pragma unroll
      for (int r = 0; r < 4; ++r) {
        const int v = tt * 4 + r;
        float d = fmaf(-2.f, acc[tt][r], wn);
        bool lt = d < d1[v];
        d2[v] = lt ? d1[v] : fminf(d2[v], d);
        d1[v] = lt ? d : d1[v];
        i1[v] = lt ? code : i1[v];
      }

    asm volatile("s_waitcnt vmcnt(0)" ::: "memory");
    __syncthreads();
  }

  #pragma unroll
  for (int m = 1; m < 16; m <<= 1) {
    #pragma unroll
    for (int v = 0; v < 8; ++v) {
      float od1 = __shfl_xor(d1[v], m, 64);
      float od2 = __shfl_xor(d2[v], m, 64);
      int   oi1 = __shfl_xor(i1[v], m, 64);
      d2[v] = fminf(fminf(d2[v], od2), fmaxf(d1[v], od1));
      bool take = (od1 < d1[v]) || (od1 == d1[v] && oi1 < i1[v]);
      d1[v] = take ? od1 : d1[v];
      i1[v] = take ? oi1 : i1[v];
    }
  }

  if (lr == 0) {
    #pragma unroll
    for (int tt = 0; tt < 2; ++tt)
      #pragma unroll
      for (int r = 0; r < 4; ++r) {
        int v = tt * 4 + r;
        int token = trow0 + tt * 16 + lq * 4 + r;
        cand[g * N_TOK + token] = d1[v];
        ((int*)cand)[CAND_I1 + g * N_TOK + token] = i1[v];
        cand[CAND_D2 + g * N_TOK + token] = d2[v];
      }
  }
}

// ---------------------------------------------------------------------------
// K1b: zero cluster-size accumulators. After k_argmin (B'' overlaps CS).
__global__ void k_zcs(float* __restrict__ out) {
  out[OFF_CS + blockIdx.x * 256 + threadIdx.x] = 0.f;
}

// ---------------------------------------------------------------------------
// K2: merge GROUPS candidates (exact 2-min); idx + margin flags (in dead-B''
// scratch, NOT z_q region: k_embed reads A' later); packed-slot init.
__global__ void k_reduce(const float* __restrict__ cand, int* __restrict__ idx,
                         int* __restrict__ flags, int* __restrict__ fcnt,
                         unsigned long long* __restrict__ packed) {
  int n = blockIdx.x * 256 + threadIdx.x;
  const int* ci = (const int*)cand + CAND_I1;
  float D1 = cand[n]; int I1 = ci[n]; float D2 = cand[CAND_D2 + n];
  #pragma unroll
  for (int g = 1; g < GROUPS; ++g) {
    float d = cand[g * N_TOK + n];
    int   i = ci[g * N_TOK + n];
    float dd = cand[CAND_D2 + g * N_TOK + n];
    D2 = fminf(fminf(D2, dd), fmaxf(D1, d));
    bool take = (d < D1) || (d == D1 && i < I1);
    D1 = take ? d : D1; I1 = take ? i : I1;
  }
  idx[n] = I1;
  if (D2 - D1 < MARGIN) {
    packed[n] = ~0ull;
    int p = atomicAdd(fcnt, 1);
    flags[p] = n;
  }
}

// ---------------------------------------------------------------------------
// K2b: exact fp32 refine, wave-per-code (R24 structure).
__global__ void k_refine(const float* __restrict__ z, const float* __restrict__ weight,
                         const float* __restrict__ wnorm, const int* __restrict__ flags,
                         const int* __restrict__ fcnt,
                         unsigned long long* __restrict__ packed) {
  const int cnt = *fcnt;
  const int lane = threadIdx.x & 63;
  const int wv = threadIdx.x >> 6;
  for (int w = blockIdx.x; w < cnt * 8; w += gridDim.x) {
    const int f = w >> 3, sub = w & 7;
    const int n = flags[f];
    const int b = n >> 10, hw = n & 1023;
    const float zd = z[b * 65536 + lane * 1024 + hw];
    float bd = 3.4e38f; int bi = 0;
    const int k0 = sub * 1024 + wv * 256;
    #pragma unroll 4
    for (int i = 0; i < 256; ++i) {
      const int k = k0 + i;
      float prod = zd * weight[k * EMB_D + lane];
      #pragma unroll
      for (int off = 32; off > 0; off >>= 1) prod += __shfl_xor(prod, off, 64);
      float dist = fmaf(-2.f, prod, wnorm[k]);
      if (dist < bd) { bd = dist; bi = k; }
    }
    if (lane == 0) {
      unsigned int bits = __float_as_uint(bd);
      unsigned int u = (bits & 0x80000000u) ? ~bits : (bits | 0x80000000u);
      atomicMin(packed + n, ((unsigned long long)u << 32) | (unsigned int)bi);
    }
  }
}

// ---------------------------------------------------------------------------
// K2b2: unpack refined winners into idx (flagged tokens only).
__global__ void k_unpack(const unsigned long long* __restrict__ packed,
                         const int* __restrict__ flags, const int* __restrict__ fcnt,
                         int* __restrict__ idx) {
  int i = blockIdx.x * 256 + threadIdx.x;
  if (i < *fcnt) {
    int n = flags[i];
    idx[n] = (int)(packed[n] & 0xffffffffull);
  }
}

// ---------------------------------------------------------------------------
// K2c: enc counts from FINAL idx (CS zeroed by k_zcs).
__global__ void k_enc(const int* __restrict__ idx, float* __restrict__ enc) {
  int n = blockIdx.x * 256 + threadIdx.x;
  atomicAdd(enc + idx[n], 1.0f);
}

// ---------------------------------------------------------------------------
// K2e: exclusive prefix-sum of the 8192 float counts -> offs + cursors.
// Single block, 256 threads x 32 elements; serial 256-partial scan by t0.
__global__ void k_scan(const float* __restrict__ cnt, int* __restrict__ offs,
                       int* __restrict__ curs) {
  __shared__ int part[256];
  const int t = threadIdx.x;
  const int base = t * 32;
  int local[32];
  int s = 0;
  #pragma unroll
  for (int i = 0; i < 32; ++i) { local[i] = s; s += (int)cnt[base + i]; }
  part[t] = s;
  __syncthreads();
  if (t == 0) {
    int run = 0;
    for (int i = 0; i < 256; ++i) { int v = part[i]; part[i] = run; run += v; }
  }
  __syncthreads();
  const int p = part[t];
  #pragma unroll
  for (int i = 0; i < 32; ++i) {
    offs[base + i] = p + local[i];
    curs[base + i] = p + local[i];
  }
}

// ---------------------------------------------------------------------------
// K2f: scatter token ids grouped by code (16K atomics over 8K cursors).
__global__ void k_scatter(const int* __restrict__ idx, int* __restrict__ curs,
                          int* __restrict__ toklist) {
  int n = blockIdx.x * 256 + threadIdx.x;
  int k = idx[n];
  int pos = atomicAdd(curs + k, 1);
  toklist[pos] = n;
}

// ---------------------------------------------------------------------------
// K2g: segmented embed_sum, wave per code, NO atomics. Lane d sums zh+zl
// from token-major A' rows (two coalesced 128B u16 wave-loads per token);
// one coalesced 256B store per code. Fully overwrites the EA region
// (cand/packed dead). MUST run before k_quant overwrites A' with z_q.
__global__ void k_embed(const unsigned short* __restrict__ A,
                        const float* __restrict__ cnt,
                        const int* __restrict__ offs,
                        const int* __restrict__ toklist,
                        float* __restrict__ embed) {
  const int lane = threadIdx.x & 63;
  const int k = blockIdx.x * 4 + (threadIdx.x >> 6);
  const int m = (int)cnt[k];
  const int off = offs[k];
  float s = 0.f;
  for (int i = 0; i < m; ++i) {
    const unsigned short* row = A + (size_t)toklist[off + i] * 128;
    s += bf2f(row[lane]) + bf2f(row[64 + lane]);
  }
  embed[k * EMB_D + lane] = s;
}

// ---------------------------------------------------------------------------
// K3: z_q gather + straight-through output + loss partials (no embed atomics).
__global__ void k_quant(const float* __restrict__ z, const float* __restrict__ weight,
                        const int* __restrict__ idx, float* __restrict__ out,
                        float* __restrict__ ws) {
  int base = blockIdx.x * 1024 + threadIdx.x;
  float lsum = 0.f;
  #pragma unroll
  for (int i = 0; i < 4; ++i) {
    int e = base + i * 256;               // (b,c,hw) flat, same layout as z
    int c = (e >> 10) & 63;
    int n = ((e >> 16) << 10) | (e & 1023);
    int k = idx[n];
    float zv = z[e];
    float q = weight[k * EMB_D + c];
    out[e] = zv + (q - zv);               // straight-through value
    float d = q - zv;
    lsum += d * d;
  }
  #pragma unroll
  for (int off = 32; off > 0; off >>= 1) lsum += __shfl_xor(lsum, off, 64);
  __shared__ float red[4];
  int lane = threadIdx.x & 63, wv = threadIdx.x >> 6;
  if (lane == 0) red[wv] = lsum;
  __syncthreads();
  if (threadIdx.x == 0)
    atomicAdd(ws + WS_LOSS, red[0] + red[1] + red[2] + red[3]);
}

// ---------------------------------------------------------------------------
// K4: new_cluster_size (in place over enc_sum), n-sum, loss finalize.
__global__ void k_cluster(const float* __restrict__ cluster_in,
                          float* __restrict__ out, float* __restrict__ ws) {
  int k = blockIdx.x * 256 + threadIdx.x;
  float ncs = cluster_in[k] * 0.99f + 0.01f * out[OFF_CS + k];
  out[OFF_CS + k] = ncs;
  float s = ncs;
  #pragma unroll
  for (int off = 32; off > 0; off >>= 1) s += __shfl_xor(s, off, 64);
  __shared__ float red[4];
  int lane = threadIdx.x & 63, wv = threadIdx.x >> 6;
  if (lane == 0) red[wv] = s;
  __syncthreads();
  if (threadIdx.x == 0) atomicAdd(ws + WS_NSUM, red[0] + red[1] + red[2] + red[3]);
  if (blockIdx.x == 0 && threadIdx.x == 0)
    out[OFF_LOSS] = 0.25f * ws[WS_LOSS] * (1.0f / 1048576.0f);
}

// ---------------------------------------------------------------------------
// K5: smoothed cluster sizes -> new_weight; new_embed_avg (in place).
__global__ void k_final(const float* __restrict__ embed_avg,
                        float* __restrict__ out, const float* __restrict__ ws) {
  int e = blockIdx.x * 256 + threadIdx.x;   // < 524288
  int k = e >> 6;
  float ncs = out[OFF_CS + k];
  float nsum = ws[WS_NSUM];
  float sm = (ncs + 1e-5f) / (nsum + K_EMB * 1e-5f) * nsum;
  float ea = embed_avg[e] * 0.99f + 0.01f * out[OFF_EA + e];
  out[OFF_EA + e] = ea;
  out[OFF_W + e] = ea / sm;
}

// ---------------------------------------------------------------------------
extern "C" void kernel_launch(void* const* d_in, const int* in_sizes, int n_in,
                              void* d_out, int out_size, void* d_ws, size_t ws_size,
                              hipStream_t stream) {
  const float* z = (const float*)d_in[0];
  const float* weight = (const float*)d_in[1];
  const float* cluster = (const float*)d_in[2];
  const float* embed_avg = (const float*)d_in[3];
  float* out = (float*)d_out;
  float* ws = (float*)d_ws;
  float* wnorm = ws + WS_WNORM;
  int* idx = (int*)(ws + WS_IDX);
  int* fcnt = (int*)ws + WS_FCNT;
  const short* Ap = (const short*)out;                     // A' in z_q region
  const short* Bp = (const short*)((unsigned short*)out + B_BASE);
  float* cand = out + OFF_EA;
  unsigned long long* packed = (unsigned long long*)(out + PK_BASE);
  int* flags = (int*)out + SCR_FLAGS;                      // dead-B'' scratch
  int* toklist = (int*)out + SCR_TOK;
  int* offs = (int*)out + SCR_OFFS;
  int* curs = (int*)out + SCR_CURS;

  hipLaunchKernelGGL(k_prep, dim3(512), dim3(256), 0, stream, weight, out, ws);
  hipLaunchKernelGGL(k_prep_a, dim3(64), dim3(256), 0, stream, z, out);
  hipLaunchKernelGGL(k_argmin, dim3(1024), dim3(256), 0, stream,
                     Ap, Bp, wnorm, cand);
  hipLaunchKernelGGL(k_zcs, dim3(K_EMB / 256), dim3(256), 0, stream, out);
  hipLaunchKernelGGL(k_reduce, dim3(N_TOK / 256), dim3(256), 0, stream,
                     cand, idx, flags, fcnt, packed);
  hipLaunchKernelGGL(k_refine, dim3(1024), dim3(256), 0, stream,
                     z, weight, wnorm, flags, fcnt, packed);
  hipLaunchKernelGGL(k_unpack, dim3(N_TOK / 256), dim3(256), 0, stream,
                     packed, flags, fcnt, idx);
  hipLaunchKernelGGL(k_enc, dim3(N_TOK / 256), dim3(256), 0, stream,
                     idx, out + OFF_CS);
  hipLaunchKernelGGL(k_scan, dim3(1), dim3(256), 0, stream,
                     out + OFF_CS, offs, curs);
  hipLaunchKernelGGL(k_scatter, dim3(N_TOK / 256), dim3(256), 0, stream,
                     idx, curs, toklist);
  hipLaunchKernelGGL(k_embed, dim3(K_EMB / 4), dim3(256), 0, stream,
                     (const unsigned short*)out, out + OFF_CS, offs, toklist,
                     out + OFF_EA);
  hipLaunchKernelGGL(k_quant, dim3(1024), dim3(256), 0, stream,
                     z, weight, idx, out, ws);
  hipLaunchKernelGGL(k_cluster, dim3(K_EMB / 256), dim3(256), 0, stream,
                     cluster, out, ws);
  hipLaunchKernelGGL(k_final, dim3(524288 / 256), dim3(256), 0, stream,
                     embed_avg, out, ws);
}

// Round 10
// 243.469 us; speedup vs baseline: 2.5223x; 1.1735x over previous
//
#include <hip/hip_runtime.h>

// EMA Vector-Quantizer for MI355X (gfx950).
// N=16384 tokens, D=64, K=8192.
// R17-R19: fp32 VALU distance GEMM plateau 203us (no fp32 MFMA on CDNA4).
// R20-R23: bf16 hi/lo split GEMM on matrix pipe + exact-margin fp32 refine.
// R24: wave-per-code refine. R25: atomic-free embed via counting sort ->
// 285.7us; k_argmin top @80us (Mfma 36%, VALU 50%, occ 32%): the ~14%
// dead time is the per-chunk vmcnt(0) full drain (gload issued and waited
// within the SAME chunk -> L2 latency exposed 64x per block).
// R26/R27 (this; R26 run died to container infra, resubmitted unchanged):
//  - k_argmin: triple-buffered chunks + counted vmcnt(1) + raw s_barrier
//    (chunk c issues c+2, waits only for c+1 -> latency hidden across 2
//    chunks). __syncthreads would re-insert the full drain; use asm+builtin.
//    vmcnt ledger: prologue {0,1}+wait(1); loop issue c+2, wait(1); c=62
//    drains to 0; c=63 clean. Barriers block-uniform -> no deadlock.
//  - drop lo*lo MFMAs (8->6/tile): |sum zl.wl| <= ~1.6e-4 -> dist err
//    ~3.3e-4, absorbed by margin.
//  - MARGIN 0.03 -> 0.01 (total err bound ~1.5e-3 -> >6x headroom);
//    ~3x fewer refine flags.
//  - k_zcs folded into k_reduce (CS zero after B'' dead; one less launch).
// Scratch liveness (out buffer):
//   A' bf16[16384][128] @ 0      : k_prep_a -> ... -> k_embed, then z_q
//   B'' @ float 1056768 (2MB)    : k_prep -> k_argmin, then int scratch
//     FLAGS@1056768 TOK@1073152 OFFS@1089536 CURS@1097736 (all < CS)
//   cand/packed in EA            : k_argmin -> k_unpack, then k_embed owns EA
//   CS counts: zeroed in k_reduce -> k_enc -> k_scan/k_cluster
// Predicted: k_argmin 80 -> 55-62us, total ~245-260us.

#define N_TOK 16384
#define K_EMB 8192
#define EMB_D 64
#define GROUPS 8

typedef short bf8 __attribute__((ext_vector_type(8)));
typedef float f32x4 __attribute__((ext_vector_type(4)));
typedef unsigned short us4 __attribute__((ext_vector_type(4)));

// d_out flat layout (float32), reference return order:
// z_q (1048576) | loss | new_weight (524288) | new_cluster_size (8192) | new_embed_avg (524288)
#define OFF_LOSS 1048576
#define OFF_W    1048577
#define OFF_CS   1572865
#define OFF_EA   1581057

// scratch offsets
#define B_BASE   2113536   // ushort index into out = byte 4227072 (16B aligned)
#define CAND_I1  131072    // within EA-based cand area (floats/ints)
#define CAND_D2  262144
#define PK_BASE  (OFF_EA + 393217)  // even float idx -> 8B-aligned u64[16384]

// int-indexed scratch in dead-B'' (W region, consumed before k_final)
#define SCR_FLAGS 1056768
#define SCR_TOK   1073152
#define SCR_OFFS  1089536
#define SCR_CURS  1097736

#define MARGIN 0.01f

// ws float offsets
#define WS_NSUM  0
#define WS_LOSS  1
#define WS_FCNT  2        // int
#define WS_WNORM 16
#define WS_IDX   (WS_WNORM + K_EMB)

__device__ __forceinline__ unsigned short f2bf(float x) {
  unsigned int b = __float_as_uint(x);
  return (unsigned short)((b + 0x7fff + ((b >> 16) & 1)) >> 16);
}
__device__ __forceinline__ float bf2f(unsigned short h) {
  return __uint_as_float(((unsigned int)h) << 16);
}

// async global->LDS, 16B per lane (dest = wave-uniform base + lane*16)
__device__ __forceinline__ void gload16(const void* g, void* l) {
  __builtin_amdgcn_global_load_lds(
      (const __attribute__((address_space(1))) void*)g,
      (__attribute__((address_space(3))) void*)l, 16, 0, 0);
}

// ---------------------------------------------------------------------------
// K0: wnorm[k]; B'' chunk layout [chunk][seg][lq][code] (shorts); ws scalars.
__global__ void k_prep(const float* __restrict__ weight,
                       float* __restrict__ out, float* __restrict__ ws) {
  int gid = blockIdx.x * 256 + threadIdx.x;     // 0..131071
  int row = gid >> 4;                            // codebook row 0..8191
  int l16 = gid & 15;
  float4 w4 = *(const float4*)(weight + row * EMB_D + l16 * 4);
  float s = w4.x * w4.x + w4.y * w4.y + w4.z * w4.z + w4.w * w4.w;
  #pragma unroll
  for (int off = 8; off > 0; off >>= 1) s += __shfl_xor(s, off, 16);
  if (l16 == 0) ws[WS_WNORM + row] = s;

  float wv[4] = {w4.x, w4.y, w4.z, w4.w};
  us4 hi, lo;
  #pragma unroll
  for (int e = 0; e < 4; ++e) {
    unsigned short h = f2bf(wv[e]);
    hi[e] = h;
    lo[e] = f2bf(wv[e] - bf2f(h));
  }
  int d0 = l16 * 4;
  int jj = d0 & 7;                 // 0 or 4
  int lqp = (d0 >> 3) & 3;
  int sp = d0 >> 5;                // 0 or 1
  unsigned short* bp = (unsigned short*)out + B_BASE
      + (row >> 4) * 2048 + (row & 15) * 8 + lqp * 128 + jj;
  *(us4*)(bp + sp * 512) = hi;
  *(us4*)(bp + (2 + sp) * 512) = lo;

  if (gid == 0) {
    out[OFF_LOSS] = 0.f; ws[WS_NSUM] = 0.f; ws[WS_LOSS] = 0.f;
    ((int*)ws)[WS_FCNT] = 0;
  }
}

// ---------------------------------------------------------------------------
// K0b: A' = [bf16_hi | bf16_lo] per token row, via LDS transpose.
__global__ void k_prep_a(const float* __restrict__ z, float* __restrict__ out) {
  __shared__ float z_s[EMB_D * 256];
  const int t = threadIdx.x;
  const int b = blockIdx.x >> 2;
  const int hw0 = (blockIdx.x & 3) * 256;
  const float* zb = z + b * 65536 + hw0;
  #pragma unroll
  for (int i = 0; i < 16; ++i) {
    int f4 = i * 256 + t;
    int d = f4 >> 6, c4 = (f4 & 63) * 4;
    *(float4*)(z_s + d * 256 + c4) = *(const float4*)(zb + d * 1024 + c4);
  }
  __syncthreads();
  int tok = b * 1024 + hw0 + t;
  unsigned short* ap = (unsigned short*)out + tok * 128;
  #pragma unroll
  for (int j = 0; j < 16; ++j) {
    us4 hi, lo;
    #pragma unroll
    for (int e = 0; e < 4; ++e) {
      float zv = z_s[(j * 4 + e) * 256 + t];
      unsigned short h = f2bf(zv);
      hi[e] = h;
      lo[e] = f2bf(zv - bf2f(h));
    }
    *(us4*)(ap + j * 4) = hi;
    *(us4*)(ap + 64 + j * 4) = lo;
  }
}

// ---------------------------------------------------------------------------
// K1: distance argmin on the matrix pipe, LDS-staged B, pipelined chunks.
// Grid 1024 blocks; g = bid&7 (XCD swizzle), tok_blk = bid>>3. Block =
// 4 waves x 32 tokens, scanning 1024 codes in 64 chunks of 16. Triple-
// buffered: chunk c issues gload(c+2), computes on buf[c], then
// vmcnt(1) (c+1 landed) + raw s_barrier -- never a full drain in-loop.
// 6 MFMAs/tile: hi.hi + hi.lo + lo.hi (lo.lo dropped, err <= ~3e-4).
__global__ __launch_bounds__(256, 4) void k_argmin(
    const short* __restrict__ A, const short* __restrict__ B,
    const float* __restrict__ wnorm, float* __restrict__ cand) {
  __shared__ __align__(16) short wbuf[3][2048];   // 3 x 4KB chunk buffers
  __shared__ __align__(16) float wn_s[1024];      // group wnorm
  const int t = threadIdx.x;
  const int lane = t & 63;
  const int wid = __builtin_amdgcn_readfirstlane(t >> 6);  // 0..3
  const int g = blockIdx.x & 7;
  const int tok_blk = blockIdx.x >> 3;
  const int trow0 = tok_blk * 128 + wid * 32;
  const int lr = lane & 15, lq = lane >> 4;

  // A-frags: 2 token-tiles x 4 k-segs (zh k0-31, zh k32-63, zl k0-31, zl k32-63)
  bf8 a[2][4];
  #pragma unroll
  for (int tt = 0; tt < 2; ++tt) {
    const short* ap = A + (size_t)(trow0 + tt * 16 + lr) * 128 + lq * 8;
    #pragma unroll
    for (int s = 0; s < 4; ++s) a[tt][s] = *(const bf8*)(ap + s * 32);
  }

  const short* bsrc = B + (size_t)g * 64 * 2048;

  // stage wnorm (4KB) + chunks 0,1
  *(float4*)(wn_s + t * 4) = *(const float4*)(wnorm + g * 1024 + t * 4);
  gload16(bsrc + t * 8, &wbuf[0][0] + t * 8);
  gload16(bsrc + 2048 + t * 8, &wbuf[1][0] + t * 8);
  asm volatile("s_waitcnt vmcnt(1) lgkmcnt(0)" ::: "memory");
  __builtin_amdgcn_s_barrier();

  float d1[8], d2[8]; int i1[8];
  #pragma unroll
  for (int v = 0; v < 8; ++v) { d1[v] = 3.4e38f; d2[v] = 3.4e38f; i1[v] = 0; }

  int cur = 0, stg = 2;
  for (int c = 0; c < 64; ++c) {
    if (c + 2 < 64)
      gload16(bsrc + (c + 2) * 2048 + t * 8, &wbuf[stg][0] + t * 8);

    const short* cb = &wbuf[cur][0];
    bf8 bfr[4];
    #pragma unroll
    for (int s = 0; s < 4; ++s)
      bfr[s] = *(const bf8*)(cb + s * 512 + lq * 128 + lr * 8);
    float wn = wn_s[c * 16 + lr];

    f32x4 acc[2];
    acc[0] = (f32x4)(0.f); acc[1] = (f32x4)(0.f);
    #pragma unroll
    for (int tt = 0; tt < 2; ++tt) {
      // hi.hi
      acc[tt] = __builtin_amdgcn_mfma_f32_16x16x32_bf16(a[tt][0], bfr[0], acc[tt], 0, 0, 0);
      acc[tt] = __builtin_amdgcn_mfma_f32_16x16x32_bf16(a[tt][1], bfr[1], acc[tt], 0, 0, 0);
      // hi.lo + lo.hi (lo.lo dropped; covered by margin)
      acc[tt] = __builtin_amdgcn_mfma_f32_16x16x32_bf16(a[tt][0], bfr[2], acc[tt], 0, 0, 0);
      acc[tt] = __builtin_amdgcn_mfma_f32_16x16x32_bf16(a[tt][1], bfr[3], acc[tt], 0, 0, 0);
      acc[tt] = __builtin_amdgcn_mfma_f32_16x16x32_bf16(a[tt][2], bfr[0], acc[tt], 0, 0, 0);
      acc[tt] = __builtin_amdgcn_mfma_f32_16x16x32_bf16(a[tt][3], bfr[1], acc[tt], 0, 0, 0);
    }

    const int code = g * 1024 + c * 16 + lr;
    #pragma unroll
    for (int tt = 0; tt < 2; ++tt)
      #pragma unroll
      for (int r = 0; r < 4; ++r) {
        const int v = tt * 4 + r;
        float d = fmaf(-2.f, acc[tt][r], wn);
        bool lt = d < d1[v];
        d2[v] = lt ? d1[v] : fminf(d2[v], d);
        d1[v] = lt ? d : d1[v];
        i1[v] = lt ? code : i1[v];
      }

    if (c < 63) {
      if (c + 2 < 64) asm volatile("s_waitcnt vmcnt(1)" ::: "memory");
      else            asm volatile("s_waitcnt vmcnt(0)" ::: "memory");
      __builtin_amdgcn_s_barrier();
    }
    cur = (cur == 2) ? 0 : cur + 1;
    stg = (stg == 2) ? 0 : stg + 1;
  }

  // exact 2-min merge across the 16 code-columns (lanes sharing lq);
  // ascending chunk order + index tie-break == numpy first-min.
  #pragma unroll
  for (int m = 1; m < 16; m <<= 1) {
    #pragma unroll
    for (int v = 0; v < 8; ++v) {
      float od1 = __shfl_xor(d1[v], m, 64);
      float od2 = __shfl_xor(d2[v], m, 64);
      int   oi1 = __shfl_xor(i1[v], m, 64);
      d2[v] = fminf(fminf(d2[v], od2), fmaxf(d1[v], od1));
      bool take = (od1 < d1[v]) || (od1 == d1[v] && oi1 < i1[v]);
      d1[v] = take ? od1 : d1[v];
      i1[v] = take ? oi1 : i1[v];
    }
  }

  if (lr == 0) {
    #pragma unroll
    for (int tt = 0; tt < 2; ++tt)
      #pragma unroll
      for (int r = 0; r < 4; ++r) {
        int v = tt * 4 + r;
        int token = trow0 + tt * 16 + lq * 4 + r;
        cand[g * N_TOK + token] = d1[v];
        ((int*)cand)[CAND_I1 + g * N_TOK + token] = i1[v];
        cand[CAND_D2 + g * N_TOK + token] = d2[v];
      }
  }
}

// ---------------------------------------------------------------------------
// K2: merge GROUPS candidates (exact 2-min); idx + margin flags; zero CS
// (B'' dead here; must precede k_enc). flags in dead-B'' scratch.
__global__ void k_reduce(const float* __restrict__ cand, int* __restrict__ idx,
                         int* __restrict__ flags, int* __restrict__ fcnt,
                         unsigned long long* __restrict__ packed,
                         float* __restrict__ cs) {
  int n = blockIdx.x * 256 + threadIdx.x;
  if (n < K_EMB) cs[n] = 0.f;              // folded k_zcs (R26)
  const int* ci = (const int*)cand + CAND_I1;
  float D1 = cand[n]; int I1 = ci[n]; float D2 = cand[CAND_D2 + n];
  #pragma unroll
  for (int g = 1; g < GROUPS; ++g) {
    float d = cand[g * N_TOK + n];
    int   i = ci[g * N_TOK + n];
    float dd = cand[CAND_D2 + g * N_TOK + n];
    D2 = fminf(fminf(D2, dd), fmaxf(D1, d));
    bool take = (d < D1) || (d == D1 && i < I1);
    D1 = take ? d : D1; I1 = take ? i : I1;
  }
  idx[n] = I1;
  if (D2 - D1 < MARGIN) {
    packed[n] = ~0ull;
    int p = atomicAdd(fcnt, 1);
    flags[p] = n;
  }
}

// ---------------------------------------------------------------------------
// K2b: exact fp32 refine, wave-per-code (R24 structure).
__global__ void k_refine(const float* __restrict__ z, const float* __restrict__ weight,
                         const float* __restrict__ wnorm, const int* __restrict__ flags,
                         const int* __restrict__ fcnt,
                         unsigned long long* __restrict__ packed) {
  const int cnt = *fcnt;
  const int lane = threadIdx.x & 63;
  const int wv = threadIdx.x >> 6;
  for (int w = blockIdx.x; w < cnt * 8; w += gridDim.x) {
    const int f = w >> 3, sub = w & 7;
    const int n = flags[f];
    const int b = n >> 10, hw = n & 1023;
    const float zd = z[b * 65536 + lane * 1024 + hw];
    float bd = 3.4e38f; int bi = 0;
    const int k0 = sub * 1024 + wv * 256;
    #pragma unroll 4
    for (int i = 0; i < 256; ++i) {
      const int k = k0 + i;
      float prod = zd * weight[k * EMB_D + lane];
      #pragma unroll
      for (int off = 32; off > 0; off >>= 1) prod += __shfl_xor(prod, off, 64);
      float dist = fmaf(-2.f, prod, wnorm[k]);
      if (dist < bd) { bd = dist; bi = k; }
    }
    if (lane == 0) {
      unsigned int bits = __float_as_uint(bd);
      unsigned int u = (bits & 0x80000000u) ? ~bits : (bits | 0x80000000u);
      atomicMin(packed + n, ((unsigned long long)u << 32) | (unsigned int)bi);
    }
  }
}

// ---------------------------------------------------------------------------
// K2b2: unpack refined winners into idx (flagged tokens only).
__global__ void k_unpack(const unsigned long long* __restrict__ packed,
                         const int* __restrict__ flags, const int* __restrict__ fcnt,
                         int* __restrict__ idx) {
  int i = blockIdx.x * 256 + threadIdx.x;
  if (i < *fcnt) {
    int n = flags[i];
    idx[n] = (int)(packed[n] & 0xffffffffull);
  }
}

// ---------------------------------------------------------------------------
// K2c: enc counts from FINAL idx (CS zeroed by k_reduce).
__global__ void k_enc(const int* __restrict__ idx, float* __restrict__ enc) {
  int n = blockIdx.x * 256 + threadIdx.x;
  atomicAdd(enc + idx[n], 1.0f);
}

// ---------------------------------------------------------------------------
// K2e: exclusive prefix-sum of the 8192 float counts -> offs + cursors.
__global__ void k_scan(const float* __restrict__ cnt, int* __restrict__ offs,
                       int* __restrict__ curs) {
  __shared__ int part[256];
  const int t = threadIdx.x;
  const int base = t * 32;
  int local[32];
  int s = 0;
  #pragma unroll
  for (int i = 0; i < 32; ++i) { local[i] = s; s += (int)cnt[base + i]; }
  part[t] = s;
  __syncthreads();
  if (t == 0) {
    int run = 0;
    for (int i = 0; i < 256; ++i) { int v = part[i]; part[i] = run; run += v; }
  }
  __syncthreads();
  const int p = part[t];
  #pragma unroll
  for (int i = 0; i < 32; ++i) {
    offs[base + i] = p + local[i];
    curs[base + i] = p + local[i];
  }
}

// ---------------------------------------------------------------------------
// K2f: scatter token ids grouped by code (16K atomics over 8K cursors).
__global__ void k_scatter(const int* __restrict__ idx, int* __restrict__ curs,
                          int* __restrict__ toklist) {
  int n = blockIdx.x * 256 + threadIdx.x;
  int k = idx[n];
  int pos = atomicAdd(curs + k, 1);
  toklist[pos] = n;
}

// ---------------------------------------------------------------------------
// K2g: segmented embed_sum, wave per code, NO atomics. Runs before k_quant
// overwrites A'.
__global__ void k_embed(const unsigned short* __restrict__ A,
                        const float* __restrict__ cnt,
                        const int* __restrict__ offs,
                        const int* __restrict__ toklist,
                        float* __restrict__ embed) {
  const int lane = threadIdx.x & 63;
  const int k = blockIdx.x * 4 + (threadIdx.x >> 6);
  const int m = (int)cnt[k];
  const int off = offs[k];
  float s = 0.f;
  for (int i = 0; i < m; ++i) {
    const unsigned short* row = A + (size_t)toklist[off + i] * 128;
    s += bf2f(row[lane]) + bf2f(row[64 + lane]);
  }
  embed[k * EMB_D + lane] = s;
}

// ---------------------------------------------------------------------------
// K3: z_q gather + straight-through output + loss partials.
__global__ void k_quant(const float* __restrict__ z, const float* __restrict__ weight,
                        const int* __restrict__ idx, float* __restrict__ out,
                        float* __restrict__ ws) {
  int base = blockIdx.x * 1024 + threadIdx.x;
  float lsum = 0.f;
  #pragma unroll
  for (int i = 0; i < 4; ++i) {
    int e = base + i * 256;               // (b,c,hw) flat, same layout as z
    int c = (e >> 10) & 63;
    int n = ((e >> 16) << 10) | (e & 1023);
    int k = idx[n];
    float zv = z[e];
    float q = weight[k * EMB_D + c];
    out[e] = zv + (q - zv);               // straight-through value
    float d = q - zv;
    lsum += d * d;
  }
  #pragma unroll
  for (int off = 32; off > 0; off >>= 1) lsum += __shfl_xor(lsum, off, 64);
  __shared__ float red[4];
  int lane = threadIdx.x & 63, wv = threadIdx.x >> 6;
  if (lane == 0) red[wv] = lsum;
  __syncthreads();
  if (threadIdx.x == 0)
    atomicAdd(ws + WS_LOSS, red[0] + red[1] + red[2] + red[3]);
}

// ---------------------------------------------------------------------------
// K4: new_cluster_size (in place over enc_sum), n-sum, loss finalize.
__global__ void k_cluster(const float* __restrict__ cluster_in,
                          float* __restrict__ out, float* __restrict__ ws) {
  int k = blockIdx.x * 256 + threadIdx.x;
  float ncs = cluster_in[k] * 0.99f + 0.01f * out[OFF_CS + k];
  out[OFF_CS + k] = ncs;
  float s = ncs;
  #pragma unroll
  for (int off = 32; off > 0; off >>= 1) s += __shfl_xor(s, off, 64);
  __shared__ float red[4];
  int lane = threadIdx.x & 63, wv = threadIdx.x >> 6;
  if (lane == 0) red[wv] = s;
  __syncthreads();
  if (threadIdx.x == 0) atomicAdd(ws + WS_NSUM, red[0] + red[1] + red[2] + red[3]);
  if (blockIdx.x == 0 && threadIdx.x == 0)
    out[OFF_LOSS] = 0.25f * ws[WS_LOSS] * (1.0f / 1048576.0f);
}

// ---------------------------------------------------------------------------
// K5: smoothed cluster sizes -> new_weight; new_embed_avg (in place).
__global__ void k_final(const float* __restrict__ embed_avg,
                        float* __restrict__ out, const float* __restrict__ ws) {
  int e = blockIdx.x * 256 + threadIdx.x;   // < 524288
  int k = e >> 6;
  float ncs = out[OFF_CS + k];
  float nsum = ws[WS_NSUM];
  float sm = (ncs + 1e-5f) / (nsum + K_EMB * 1e-5f) * nsum;
  float ea = embed_avg[e] * 0.99f + 0.01f * out[OFF_EA + e];
  out[OFF_EA + e] = ea;
  out[OFF_W + e] = ea / sm;
}

// ---------------------------------------------------------------------------
extern "C" void kernel_launch(void* const* d_in, const int* in_sizes, int n_in,
                              void* d_out, int out_size, void* d_ws, size_t ws_size,
                              hipStream_t stream) {
  const float* z = (const float*)d_in[0];
  const float* weight = (const float*)d_in[1];
  const float* cluster = (const float*)d_in[2];
  const float* embed_avg = (const float*)d_in[3];
  float* out = (float*)d_out;
  float* ws = (float*)d_ws;
  float* wnorm = ws + WS_WNORM;
  int* idx = (int*)(ws + WS_IDX);
  int* fcnt = (int*)ws + WS_FCNT;
  const short* Ap = (const short*)out;                     // A' in z_q region
  const short* Bp = (const short*)((unsigned short*)out + B_BASE);
  float* cand = out + OFF_EA;
  unsigned long long* packed = (unsigned long long*)(out + PK_BASE);
  int* flags = (int*)out + SCR_FLAGS;                      // dead-B'' scratch
  int* toklist = (int*)out + SCR_TOK;
  int* offs = (int*)out + SCR_OFFS;
  int* curs = (int*)out + SCR_CURS;

  hipLaunchKernelGGL(k_prep, dim3(512), dim3(256), 0, stream, weight, out, ws);
  hipLaunchKernelGGL(k_prep_a, dim3(64), dim3(256), 0, stream, z, out);
  hipLaunchKernelGGL(k_argmin, dim3(1024), dim3(256), 0, stream,
                     Ap, Bp, wnorm, cand);
  hipLaunchKernelGGL(k_reduce, dim3(N_TOK / 256), dim3(256), 0, stream,
                     cand, idx, flags, fcnt, packed, out + OFF_CS);
  hipLaunchKernelGGL(k_refine, dim3(1024), dim3(256), 0, stream,
                     z, weight, wnorm, flags, fcnt, packed);
  hipLaunchKernelGGL(k_unpack, dim3(N_TOK / 256), dim3(256), 0, stream,
                     packed, flags, fcnt, idx);
  hipLaunchKernelGGL(k_enc, dim3(N_TOK / 256), dim3(256), 0, stream,
                     idx, out + OFF_CS);
  hipLaunchKernelGGL(k_scan, dim3(1), dim3(256), 0, stream,
                     out + OFF_CS, offs, curs);
  hipLaunchKernelGGL(k_scatter, dim3(N_TOK / 256), dim3(256), 0, stream,
                     idx, curs, toklist);
  hipLaunchKernelGGL(k_embed, dim3(K_EMB / 4), dim3(256), 0, stream,
                     (const unsigned short*)out, out + OFF_CS, offs, toklist,
                     out + OFF_EA);
  hipLaunchKernelGGL(k_quant, dim3(1024), dim3(256), 0, stream,
                     z, weight, idx, out, ws);
  hipLaunchKernelGGL(k_cluster, dim3(K_EMB / 256), dim3(256), 0, stream,
                     cluster, out, ws);
  hipLaunchKernelGGL(k_final, dim3(524288 / 256), dim3(256), 0, stream,
                     embed_avg, out, ws);
}

// Round 11
// 238.735 us; speedup vs baseline: 2.5723x; 1.0198x over previous
//
#include <hip/hip_runtime.h>

// EMA Vector-Quantizer for MI355X (gfx950).
// N=16384 tokens, D=64, K=8192.
// R17-R19: fp32 VALU GEMM plateau 203us (no fp32 MFMA on CDNA4).
// R20-R23: bf16 hi/lo split GEMM on matrix pipe + exact-margin fp32 refine.
// R24: wave-per-code refine. R25: atomic-free embed (counting sort).
// R26: k_argmin triple-buffer + counted vmcnt(1) + 6 MFMAs -> 71us @ 82%
// combined pipe util (VALU-epilogue-bound: 6 ops/dot irreducible with exact
// d2). 243.5us total -> tail (~172us over 12 kernels) is now the target.
// R28 (this): tail restructure, k_argmin untouched:
//  - k_prep + k_prep_a fused (grid 576, branch).
//  - k_unpack deleted: packed[] is idx-truth (EA region, dead before
//    k_embed overwrites EA); k_enc reads packed -> writes idx + counts.
//  - k_cluster deleted: nsum closed-form = 0.99*sum(cluster_in)+163.84
//    (sum enc == N_TOK exactly); csum computed race-free in k_scan;
//    k_final computes ncs inline (per-k reads+syncthreads+single-lane CS
//    write, one block owns 4 whole k-groups -> race-free) + loss finalize.
//  13 -> 10 launches.
// Scratch liveness (out buffer):
//   A' bf16[16384][128] @ 0      : prep -> k_embed, then z_q
//   B'' @ float 1056768 (2MB)    : prep -> k_argmin, then int scratch
//     FLAGS@1056768 TOK@1073152 OFFS@1089536 CURS@1097736 (all < CS)
//   cand [EA, +393216) / packed @ PK_BASE : dead before k_embed owns EA
//   counts @ OFF_CS: zeroed in k_reduce -> k_enc -> k_scan/k_embed/k_final
// Predicted: k_argmin ~71us unchanged; total 243.5 -> ~215-225us.

#define N_TOK 16384
#define K_EMB 8192
#define EMB_D 64
#define GROUPS 8

typedef short bf8 __attribute__((ext_vector_type(8)));
typedef float f32x4 __attribute__((ext_vector_type(4)));
typedef unsigned short us4 __attribute__((ext_vector_type(4)));

// d_out flat layout (float32), reference return order:
// z_q (1048576) | loss | new_weight (524288) | new_cluster_size (8192) | new_embed_avg (524288)
#define OFF_LOSS 1048576
#define OFF_W    1048577
#define OFF_CS   1572865
#define OFF_EA   1581057

// scratch offsets
#define B_BASE   2113536   // ushort index into out = byte 4227072 (16B aligned)
#define CAND_I1  131072    // within EA-based cand area (floats/ints)
#define CAND_D2  262144
#define PK_BASE  (OFF_EA + 393217)  // even float idx -> 8B-aligned u64[16384]

// int-indexed scratch in dead-B'' (W region, consumed before k_final)
#define SCR_FLAGS 1056768
#define SCR_TOK   1073152
#define SCR_OFFS  1089536
#define SCR_CURS  1097736

#define MARGIN 0.01f

// ws float offsets
#define WS_NSUM  0
#define WS_LOSS  1
#define WS_FCNT  2        // int
#define WS_WNORM 16
#define WS_IDX   (WS_WNORM + K_EMB)   // int idx[16384]

__device__ __forceinline__ unsigned short f2bf(float x) {
  unsigned int b = __float_as_uint(x);
  return (unsigned short)((b + 0x7fff + ((b >> 16) & 1)) >> 16);
}
__device__ __forceinline__ float bf2f(unsigned short h) {
  return __uint_as_float(((unsigned int)h) << 16);
}

// async global->LDS, 16B per lane (dest = wave-uniform base + lane*16)
__device__ __forceinline__ void gload16(const void* g, void* l) {
  __builtin_amdgcn_global_load_lds(
      (const __attribute__((address_space(1))) void*)g,
      (__attribute__((address_space(3))) void*)l, 16, 0, 0);
}

// ---------------------------------------------------------------------------
// K0 (fused): blocks 0..511: wnorm[k] + B'' chunk layout + ws scalars.
// Blocks 512..575: A' = [bf16_hi | bf16_lo] per token row via LDS transpose.
__global__ void k_prep(const float* __restrict__ weight, const float* __restrict__ z,
                       float* __restrict__ out, float* __restrict__ ws) {
  __shared__ float z_s[EMB_D * 256];
  if (blockIdx.x < 512) {
    int gid = blockIdx.x * 256 + threadIdx.x;     // 0..131071
    int row = gid >> 4;                            // codebook row 0..8191
    int l16 = gid & 15;
    float4 w4 = *(const float4*)(weight + row * EMB_D + l16 * 4);
    float s = w4.x * w4.x + w4.y * w4.y + w4.z * w4.z + w4.w * w4.w;
    #pragma unroll
    for (int off = 8; off > 0; off >>= 1) s += __shfl_xor(s, off, 16);
    if (l16 == 0) ws[WS_WNORM + row] = s;

    float wv[4] = {w4.x, w4.y, w4.z, w4.w};
    us4 hi, lo;
    #pragma unroll
    for (int e = 0; e < 4; ++e) {
      unsigned short h = f2bf(wv[e]);
      hi[e] = h;
      lo[e] = f2bf(wv[e] - bf2f(h));
    }
    int d0 = l16 * 4;
    int jj = d0 & 7;                 // 0 or 4
    int lqp = (d0 >> 3) & 3;
    int sp = d0 >> 5;                // 0 or 1
    unsigned short* bp = (unsigned short*)out + B_BASE
        + (row >> 4) * 2048 + (row & 15) * 8 + lqp * 128 + jj;
    *(us4*)(bp + sp * 512) = hi;
    *(us4*)(bp + (2 + sp) * 512) = lo;

    if (gid == 0) {
      out[OFF_LOSS] = 0.f; ws[WS_LOSS] = 0.f;
      ((int*)ws)[WS_FCNT] = 0;
    }
  } else {
    const int t = threadIdx.x;
    const int pb = blockIdx.x - 512;              // 0..63
    const int b = pb >> 2;
    const int hw0 = (pb & 3) * 256;
    const float* zb = z + b * 65536 + hw0;
    #pragma unroll
    for (int i = 0; i < 16; ++i) {
      int f4 = i * 256 + t;
      int d = f4 >> 6, c4 = (f4 & 63) * 4;
      *(float4*)(z_s + d * 256 + c4) = *(const float4*)(zb + d * 1024 + c4);
    }
    __syncthreads();
    int tok = b * 1024 + hw0 + t;
    unsigned short* ap = (unsigned short*)out + tok * 128;
    #pragma unroll
    for (int j = 0; j < 16; ++j) {
      us4 hi, lo;
      #pragma unroll
      for (int e = 0; e < 4; ++e) {
        float zv = z_s[(j * 4 + e) * 256 + t];
        unsigned short h = f2bf(zv);
        hi[e] = h;
        lo[e] = f2bf(zv - bf2f(h));
      }
      *(us4*)(ap + j * 4) = hi;
      *(us4*)(ap + 64 + j * 4) = lo;
    }
  }
}

// ---------------------------------------------------------------------------
// K1: distance argmin on the matrix pipe (unchanged from R26; 71us, 82%
// combined pipe util, VALU-epilogue-bound).
__global__ __launch_bounds__(256, 4) void k_argmin(
    const short* __restrict__ A, const short* __restrict__ B,
    const float* __restrict__ wnorm, float* __restrict__ cand) {
  __shared__ __align__(16) short wbuf[3][2048];   // 3 x 4KB chunk buffers
  __shared__ __align__(16) float wn_s[1024];      // group wnorm
  const int t = threadIdx.x;
  const int lane = t & 63;
  const int wid = __builtin_amdgcn_readfirstlane(t >> 6);  // 0..3
  const int g = blockIdx.x & 7;
  const int tok_blk = blockIdx.x >> 3;
  const int trow0 = tok_blk * 128 + wid * 32;
  const int lr = lane & 15, lq = lane >> 4;

  bf8 a[2][4];
  #pragma unroll
  for (int tt = 0; tt < 2; ++tt) {
    const short* ap = A + (size_t)(trow0 + tt * 16 + lr) * 128 + lq * 8;
    #pragma unroll
    for (int s = 0; s < 4; ++s) a[tt][s] = *(const bf8*)(ap + s * 32);
  }

  const short* bsrc = B + (size_t)g * 64 * 2048;

  *(float4*)(wn_s + t * 4) = *(const float4*)(wnorm + g * 1024 + t * 4);
  gload16(bsrc + t * 8, &wbuf[0][0] + t * 8);
  gload16(bsrc + 2048 + t * 8, &wbuf[1][0] + t * 8);
  asm volatile("s_waitcnt vmcnt(1) lgkmcnt(0)" ::: "memory");
  __builtin_amdgcn_s_barrier();

  float d1[8], d2[8]; int i1[8];
  #pragma unroll
  for (int v = 0; v < 8; ++v) { d1[v] = 3.4e38f; d2[v] = 3.4e38f; i1[v] = 0; }

  int cur = 0, stg = 2;
  for (int c = 0; c < 64; ++c) {
    if (c + 2 < 64)
      gload16(bsrc + (c + 2) * 2048 + t * 8, &wbuf[stg][0] + t * 8);

    const short* cb = &wbuf[cur][0];
    bf8 bfr[4];
    #pragma unroll
    for (int s = 0; s < 4; ++s)
      bfr[s] = *(const bf8*)(cb + s * 512 + lq * 128 + lr * 8);
    float wn = wn_s[c * 16 + lr];

    f32x4 acc[2];
    acc[0] = (f32x4)(0.f); acc[1] = (f32x4)(0.f);
    #pragma unroll
    for (int tt = 0; tt < 2; ++tt) {
      acc[tt] = __builtin_amdgcn_mfma_f32_16x16x32_bf16(a[tt][0], bfr[0], acc[tt], 0, 0, 0);
      acc[tt] = __builtin_amdgcn_mfma_f32_16x16x32_bf16(a[tt][1], bfr[1], acc[tt], 0, 0, 0);
      acc[tt] = __builtin_amdgcn_mfma_f32_16x16x32_bf16(a[tt][0], bfr[2], acc[tt], 0, 0, 0);
      acc[tt] = __builtin_amdgcn_mfma_f32_16x16x32_bf16(a[tt][1], bfr[3], acc[tt], 0, 0, 0);
      acc[tt] = __builtin_amdgcn_mfma_f32_16x16x32_bf16(a[tt][2], bfr[0], acc[tt], 0, 0, 0);
      acc[tt] = __builtin_amdgcn_mfma_f32_16x16x32_bf16(a[tt][3], bfr[1], acc[tt], 0, 0, 0);
    }

    const int code = g * 1024 + c * 16 + lr;
    #pragma unroll
    for (int tt = 0; tt < 2; ++tt)
      #pragma unroll
      for (int r = 0; r < 4; ++r) {
        const int v = tt * 4 + r;
        float d = fmaf(-2.f, acc[tt][r], wn);
        bool lt = d < d1[v];
        d2[v] = lt ? d1[v] : fminf(d2[v], d);
        d1[v] = lt ? d : d1[v];
        i1[v] = lt ? code : i1[v];
      }

    if (c < 63) {
      if (c + 2 < 64) asm volatile("s_waitcnt vmcnt(1)" ::: "memory");
      else            asm volatile("s_waitcnt vmcnt(0)" ::: "memory");
      __builtin_amdgcn_s_barrier();
    }
    cur = (cur == 2) ? 0 : cur + 1;
    stg = (stg == 2) ? 0 : stg + 1;
  }

  #pragma unroll
  for (int m = 1; m < 16; m <<= 1) {
    #pragma unroll
    for (int v = 0; v < 8; ++v) {
      float od1 = __shfl_xor(d1[v], m, 64);
      float od2 = __shfl_xor(d2[v], m, 64);
      int   oi1 = __shfl_xor(i1[v], m, 64);
      d2[v] = fminf(fminf(d2[v], od2), fmaxf(d1[v], od1));
      bool take = (od1 < d1[v]) || (od1 == d1[v] && oi1 < i1[v]);
      d1[v] = take ? od1 : d1[v];
      i1[v] = take ? oi1 : i1[v];
    }
  }

  if (lr == 0) {
    #pragma unroll
    for (int tt = 0; tt < 2; ++tt)
      #pragma unroll
      for (int r = 0; r < 4; ++r) {
        int v = tt * 4 + r;
        int token = trow0 + tt * 16 + lq * 4 + r;
        cand[g * N_TOK + token] = d1[v];
        ((int*)cand)[CAND_I1 + g * N_TOK + token] = i1[v];
        cand[CAND_D2 + g * N_TOK + token] = d2[v];
      }
  }
}

// ---------------------------------------------------------------------------
// K2: merge GROUPS candidates (exact 2-min); packed (idx-truth) + margin
// flags; zero counts (B'' dead here; must precede k_enc).
__global__ void k_reduce(const float* __restrict__ cand, int* __restrict__ flags,
                         int* __restrict__ fcnt,
                         unsigned long long* __restrict__ packed,
                         float* __restrict__ cs) {
  int n = blockIdx.x * 256 + threadIdx.x;
  if (n < K_EMB) cs[n] = 0.f;              // counts accumulator zero
  const int* ci = (const int*)cand + CAND_I1;
  float D1 = cand[n]; int I1 = ci[n]; float D2 = cand[CAND_D2 + n];
  #pragma unroll
  for (int g = 1; g < GROUPS; ++g) {
    float d = cand[g * N_TOK + n];
    int   i = ci[g * N_TOK + n];
    float dd = cand[CAND_D2 + g * N_TOK + n];
    D2 = fminf(fminf(D2, dd), fmaxf(D1, d));
    bool take = (d < D1) || (d == D1 && i < I1);
    D1 = take ? d : D1; I1 = take ? i : I1;
  }
  if (D2 - D1 < MARGIN) {
    packed[n] = ~0ull;                     // refine will atomicMin exact vals
    int p = atomicAdd(fcnt, 1);
    flags[p] = n;
  } else {
    unsigned int bits = __float_as_uint(D1);
    unsigned int u = (bits & 0x80000000u) ? ~bits : (bits | 0x80000000u);
    packed[n] = ((unsigned long long)u << 32) | (unsigned int)I1;
  }
}

// ---------------------------------------------------------------------------
// K2b: exact fp32 refine, wave-per-code (R24 structure).
__global__ void k_refine(const float* __restrict__ z, const float* __restrict__ weight,
                         const float* __restrict__ wnorm, const int* __restrict__ flags,
                         const int* __restrict__ fcnt,
                         unsigned long long* __restrict__ packed) {
  const int cnt = *fcnt;
  const int lane = threadIdx.x & 63;
  const int wv = threadIdx.x >> 6;
  for (int w = blockIdx.x; w < cnt * 8; w += gridDim.x) {
    const int f = w >> 3, sub = w & 7;
    const int n = flags[f];
    const int b = n >> 10, hw = n & 1023;
    const float zd = z[b * 65536 + lane * 1024 + hw];
    float bd = 3.4e38f; int bi = 0;
    const int k0 = sub * 1024 + wv * 256;
    #pragma unroll 4
    for (int i = 0; i < 256; ++i) {
      const int k = k0 + i;
      float prod = zd * weight[k * EMB_D + lane];
      #pragma unroll
      for (int off = 32; off > 0; off >>= 1) prod += __shfl_xor(prod, off, 64);
      float dist = fmaf(-2.f, prod, wnorm[k]);
      if (dist < bd) { bd = dist; bi = k; }
    }
    if (lane == 0) {
      unsigned int bits = __float_as_uint(bd);
      unsigned int u = (bits & 0x80000000u) ? ~bits : (bits | 0x80000000u);
      atomicMin(packed + n, ((unsigned long long)u << 32) | (unsigned int)bi);
    }
  }
}

// ---------------------------------------------------------------------------
// K2c: idx + enc counts from packed (post-refine truth).
__global__ void k_enc(const unsigned long long* __restrict__ packed,
                      int* __restrict__ idx, float* __restrict__ cnt) {
  int n = blockIdx.x * 256 + threadIdx.x;
  int k = (int)(packed[n] & 0xffffffffull);
  idx[n] = k;
  atomicAdd(cnt + k, 1.0f);
}

// ---------------------------------------------------------------------------
// K2e: exclusive prefix-sum of counts -> offs + cursors; also nsum
// closed-form: 0.99*sum(cluster_in) + 0.01*N_TOK (sum enc == N_TOK exact).
__global__ void k_scan(const float* __restrict__ cnt,
                       const float* __restrict__ cluster_in,
                       int* __restrict__ offs, int* __restrict__ curs,
                       float* __restrict__ ws) {
  __shared__ int part[256];
  __shared__ float fpart[256];
  const int t = threadIdx.x;
  const int base = t * 32;
  int local[32];
  int s = 0;
  #pragma unroll
  for (int i = 0; i < 32; ++i) { local[i] = s; s += (int)cnt[base + i]; }
  part[t] = s;
  float csl = 0.f;
  #pragma unroll
  for (int i = 0; i < 32; ++i) csl += cluster_in[base + i];
  fpart[t] = csl;
  __syncthreads();
  if (t == 0) {
    int run = 0;
    for (int i = 0; i < 256; ++i) { int v = part[i]; part[i] = run; run += v; }
    float cs2 = 0.f;
    for (int i = 0; i < 256; ++i) cs2 += fpart[i];
    ws[WS_NSUM] = 0.99f * cs2 + 0.01f * (float)N_TOK;
  }
  __syncthreads();
  const int p = part[t];
  #pragma unroll
  for (int i = 0; i < 32; ++i) {
    offs[base + i] = p + local[i];
    curs[base + i] = p + local[i];
  }
}

// ---------------------------------------------------------------------------
// K2f: scatter token ids grouped by code (16K atomics over 8K cursors).
__global__ void k_scatter(const int* __restrict__ idx, int* __restrict__ curs,
                          int* __restrict__ toklist) {
  int n = blockIdx.x * 256 + threadIdx.x;
  int k = idx[n];
  int pos = atomicAdd(curs + k, 1);
  toklist[pos] = n;
}

// ---------------------------------------------------------------------------
// K2g: segmented embed_sum, wave per code, NO atomics. Overwrites EA
// (cand/packed dead). Runs before k_quant overwrites A'.
__global__ void k_embed(const unsigned short* __restrict__ A,
                        const float* __restrict__ cnt,
                        const int* __restrict__ offs,
                        const int* __restrict__ toklist,
                        float* __restrict__ embed) {
  const int lane = threadIdx.x & 63;
  const int k = blockIdx.x * 4 + (threadIdx.x >> 6);
  const int m = (int)cnt[k];
  const int off = offs[k];
  float s = 0.f;
  for (int i = 0; i < m; ++i) {
    const unsigned short* row = A + (size_t)toklist[off + i] * 128;
    s += bf2f(row[lane]) + bf2f(row[64 + lane]);
  }
  embed[k * EMB_D + lane] = s;
}

// ---------------------------------------------------------------------------
// K3: z_q gather + straight-through output + loss partials.
__global__ void k_quant(const float* __restrict__ z, const float* __restrict__ weight,
                        const int* __restrict__ idx, float* __restrict__ out,
                        float* __restrict__ ws) {
  int base = blockIdx.x * 1024 + threadIdx.x;
  float lsum = 0.f;
  #pragma unroll
  for (int i = 0; i < 4; ++i) {
    int e = base + i * 256;               // (b,c,hw) flat, same layout as z
    int c = (e >> 10) & 63;
    int n = ((e >> 16) << 10) | (e & 1023);
    int k = idx[n];
    float zv = z[e];
    float q = weight[k * EMB_D + c];
    out[e] = zv + (q - zv);               // straight-through value
    float d = q - zv;
    lsum += d * d;
  }
  #pragma unroll
  for (int off = 32; off > 0; off >>= 1) lsum += __shfl_xor(lsum, off, 64);
  __shared__ float red[4];
  int lane = threadIdx.x & 63, wv = threadIdx.x >> 6;
  if (lane == 0) red[wv] = lsum;
  __syncthreads();
  if (threadIdx.x == 0)
    atomicAdd(ws + WS_LOSS, red[0] + red[1] + red[2] + red[3]);
}

// ---------------------------------------------------------------------------
// K5 (fused cluster+final): ncs computed inline from raw counts; CS written
// once per k by the (e&63)==0 lane AFTER all block-local cnt reads (one
// block owns 4 whole k-groups -> no cross-block RMW race). nsum precomputed
// (k_scan). Loss finalized here (after k_quant).
__global__ void k_final(const float* __restrict__ cluster_in,
                        const float* __restrict__ embed_avg,
                        float* __restrict__ out, const float* __restrict__ ws) {
  int e = blockIdx.x * 256 + threadIdx.x;   // < 524288
  int k = e >> 6;
  float cntk = out[OFF_CS + k];             // raw count
  float ncs = cluster_in[k] * 0.99f + 0.01f * cntk;
  float nsum = ws[WS_NSUM];
  float sm = (ncs + 1e-5f) / (nsum + K_EMB * 1e-5f) * nsum;
  float ea = embed_avg[e] * 0.99f + 0.01f * out[OFF_EA + e];
  __syncthreads();                          // all cnt reads in block done
  if ((e & 63) == 0) out[OFF_CS + k] = ncs;
  out[OFF_EA + e] = ea;
  out[OFF_W + e] = ea / sm;
  if (e == 0)
    out[OFF_LOSS] = 0.25f * ws[WS_LOSS] * (1.0f / 1048576.0f);
}

// ---------------------------------------------------------------------------
extern "C" void kernel_launch(void* const* d_in, const int* in_sizes, int n_in,
                              void* d_out, int out_size, void* d_ws, size_t ws_size,
                              hipStream_t stream) {
  const float* z = (const float*)d_in[0];
  const float* weight = (const float*)d_in[1];
  const float* cluster = (const float*)d_in[2];
  const float* embed_avg = (const float*)d_in[3];
  float* out = (float*)d_out;
  float* ws = (float*)d_ws;
  float* wnorm = ws + WS_WNORM;
  int* idx = (int*)(ws + WS_IDX);
  int* fcnt = (int*)ws + WS_FCNT;
  const short* Ap = (const short*)out;                     // A' in z_q region
  const short* Bp = (const short*)((unsigned short*)out + B_BASE);
  float* cand = out + OFF_EA;
  unsigned long long* packed = (unsigned long long*)(out + PK_BASE);
  int* flags = (int*)out + SCR_FLAGS;                      // dead-B'' scratch
  int* toklist = (int*)out + SCR_TOK;
  int* offs = (int*)out + SCR_OFFS;
  int* curs = (int*)out + SCR_CURS;

  hipLaunchKernelGGL(k_prep, dim3(576), dim3(256), 0, stream, weight, z, out, ws);
  hipLaunchKernelGGL(k_argmin, dim3(1024), dim3(256), 0, stream,
                     Ap, Bp, wnorm, cand);
  hipLaunchKernelGGL(k_reduce, dim3(N_TOK / 256), dim3(256), 0, stream,
                     cand, flags, fcnt, packed, out + OFF_CS);
  hipLaunchKernelGGL(k_refine, dim3(1024), dim3(256), 0, stream,
                     z, weight, wnorm, flags, fcnt, packed);
  hipLaunchKernelGGL(k_enc, dim3(N_TOK / 256), dim3(256), 0, stream,
                     packed, idx, out + OFF_CS);
  hipLaunchKernelGGL(k_scan, dim3(1), dim3(256), 0, stream,
                     out + OFF_CS, cluster, offs, curs, ws);
  hipLaunchKernelGGL(k_scatter, dim3(N_TOK / 256), dim3(256), 0, stream,
                     idx, curs, toklist);
  hipLaunchKernelGGL(k_embed, dim3(K_EMB / 4), dim3(256), 0, stream,
                     (const unsigned short*)out, out + OFF_CS, offs, toklist,
                     out + OFF_EA);
  hipLaunchKernelGGL(k_quant, dim3(1024), dim3(256), 0, stream,
                     z, weight, idx, out, ws);
  hipLaunchKernelGGL(k_final, dim3(524288 / 256), dim3(256), 0, stream,
                     cluster, embed_avg, out, ws);
}

// Round 12
// 236.994 us; speedup vs baseline: 2.5912x; 1.0073x over previous
//
#include <hip/hip_runtime.h>

// EMA Vector-Quantizer for MI355X (gfx950).
// N=16384 tokens, D=64, K=8192.
// R17-R19: fp32 VALU GEMM plateau 203us (no fp32 MFMA on CDNA4).
// R20-R23: bf16 hi/lo split GEMM on matrix pipe + exact-margin fp32 refine.
// R24: wave-per-code refine. R25: atomic-free embed (counting sort).
// R26: k_argmin triple-buffer + counted vmcnt(1) + 6 MFMAs -> ~73us @ 83%
// combined pipe util. R28: tail fusion -> 238.7us; launch gaps ~1.7us each
// (tail is work-bound, not launch-bound).
// R29 (this):
//  - k_argmin epilogue 6->5 ops/dot: exact top-2 via v_med3_f32
//    (d2 = median(d1,d2,d) -- exact since d1<=d2 invariant; d1 = fmin;
//    i1 = cmp+sel). Epilogue 48->40 wave-inst/chunk.
//  - k_quant x4: 4 consecutive e = same (b,c), 4 consecutive tokens ->
//    float4 z/out + int4 idx; weight gather stays scalar.
//  - k_final x4: 4 consecutive e share one k -> float4 EA/W streams,
//    grid 2048->512; CS write still one-lane-per-k, block-owns-k.
// Scratch liveness (out buffer):
//   A' bf16[16384][128] @ 0      : prep -> k_embed, then z_q
//   B'' @ float 1056768 (2MB)    : prep -> k_argmin, then int scratch
//     FLAGS@1056768 TOK@1073152 OFFS@1089536 CURS@1097736 (all < CS)
//   cand [EA, +393216) / packed @ PK_BASE : dead before k_embed owns EA
//   counts @ OFF_CS: zeroed in k_reduce -> k_enc -> k_scan/k_embed/k_final
// Predicted: k_argmin ~67us, total ~222-228us.

#define N_TOK 16384
#define K_EMB 8192
#define EMB_D 64
#define GROUPS 8

typedef short bf8 __attribute__((ext_vector_type(8)));
typedef float f32x4 __attribute__((ext_vector_type(4)));
typedef unsigned short us4 __attribute__((ext_vector_type(4)));

// d_out flat layout (float32), reference return order:
// z_q (1048576) | loss | new_weight (524288) | new_cluster_size (8192) | new_embed_avg (524288)
#define OFF_LOSS 1048576
#define OFF_W    1048577
#define OFF_CS   1572865
#define OFF_EA   1581057

// scratch offsets
#define B_BASE   2113536   // ushort index into out = byte 4227072 (16B aligned)
#define CAND_I1  131072    // within EA-based cand area (floats/ints)
#define CAND_D2  262144
#define PK_BASE  (OFF_EA + 393217)  // even float idx -> 8B-aligned u64[16384]

// int-indexed scratch in dead-B'' (W region, consumed before k_final)
#define SCR_FLAGS 1056768
#define SCR_TOK   1073152
#define SCR_OFFS  1089536
#define SCR_CURS  1097736

#define MARGIN 0.01f

// ws float offsets
#define WS_NSUM  0
#define WS_LOSS  1
#define WS_FCNT  2        // int
#define WS_WNORM 16
#define WS_IDX   (WS_WNORM + K_EMB)   // int idx[16384]

__device__ __forceinline__ unsigned short f2bf(float x) {
  unsigned int b = __float_as_uint(x);
  return (unsigned short)((b + 0x7fff + ((b >> 16) & 1)) >> 16);
}
__device__ __forceinline__ float bf2f(unsigned short h) {
  return __uint_as_float(((unsigned int)h) << 16);
}

// async global->LDS, 16B per lane (dest = wave-uniform base + lane*16)
__device__ __forceinline__ void gload16(const void* g, void* l) {
  __builtin_amdgcn_global_load_lds(
      (const __attribute__((address_space(1))) void*)g,
      (__attribute__((address_space(3))) void*)l, 16, 0, 0);
}

// ---------------------------------------------------------------------------
// K0 (fused): blocks 0..511: wnorm[k] + B'' chunk layout + ws scalars.
// Blocks 512..575: A' = [bf16_hi | bf16_lo] per token row via LDS transpose.
__global__ void k_prep(const float* __restrict__ weight, const float* __restrict__ z,
                       float* __restrict__ out, float* __restrict__ ws) {
  __shared__ float z_s[EMB_D * 256];
  if (blockIdx.x < 512) {
    int gid = blockIdx.x * 256 + threadIdx.x;     // 0..131071
    int row = gid >> 4;                            // codebook row 0..8191
    int l16 = gid & 15;
    float4 w4 = *(const float4*)(weight + row * EMB_D + l16 * 4);
    float s = w4.x * w4.x + w4.y * w4.y + w4.z * w4.z + w4.w * w4.w;
    #pragma unroll
    for (int off = 8; off > 0; off >>= 1) s += __shfl_xor(s, off, 16);
    if (l16 == 0) ws[WS_WNORM + row] = s;

    float wv[4] = {w4.x, w4.y, w4.z, w4.w};
    us4 hi, lo;
    #pragma unroll
    for (int e = 0; e < 4; ++e) {
      unsigned short h = f2bf(wv[e]);
      hi[e] = h;
      lo[e] = f2bf(wv[e] - bf2f(h));
    }
    int d0 = l16 * 4;
    int jj = d0 & 7;                 // 0 or 4
    int lqp = (d0 >> 3) & 3;
    int sp = d0 >> 5;                // 0 or 1
    unsigned short* bp = (unsigned short*)out + B_BASE
        + (row >> 4) * 2048 + (row & 15) * 8 + lqp * 128 + jj;
    *(us4*)(bp + sp * 512) = hi;
    *(us4*)(bp + (2 + sp) * 512) = lo;

    if (gid == 0) {
      out[OFF_LOSS] = 0.f; ws[WS_LOSS] = 0.f;
      ((int*)ws)[WS_FCNT] = 0;
    }
  } else {
    const int t = threadIdx.x;
    const int pb = blockIdx.x - 512;              // 0..63
    const int b = pb >> 2;
    const int hw0 = (pb & 3) * 256;
    const float* zb = z + b * 65536 + hw0;
    #pragma unroll
    for (int i = 0; i < 16; ++i) {
      int f4 = i * 256 + t;
      int d = f4 >> 6, c4 = (f4 & 63) * 4;
      *(float4*)(z_s + d * 256 + c4) = *(const float4*)(zb + d * 1024 + c4);
    }
    __syncthreads();
    int tok = b * 1024 + hw0 + t;
    unsigned short* ap = (unsigned short*)out + tok * 128;
    #pragma unroll
    for (int j = 0; j < 16; ++j) {
      us4 hi, lo;
      #pragma unroll
      for (int e = 0; e < 4; ++e) {
        float zv = z_s[(j * 4 + e) * 256 + t];
        unsigned short h = f2bf(zv);
        hi[e] = h;
        lo[e] = f2bf(zv - bf2f(h));
      }
      *(us4*)(ap + j * 4) = hi;
      *(us4*)(ap + 64 + j * 4) = lo;
    }
  }
}

// ---------------------------------------------------------------------------
// K1: distance argmin on the matrix pipe. R26 pipeline (triple buffer,
// counted vmcnt, 6 MFMAs) + R29 med3 epilogue (5 ops/dot, exact top-2).
__global__ __launch_bounds__(256, 4) void k_argmin(
    const short* __restrict__ A, const short* __restrict__ B,
    const float* __restrict__ wnorm, float* __restrict__ cand) {
  __shared__ __align__(16) short wbuf[3][2048];   // 3 x 4KB chunk buffers
  __shared__ __align__(16) float wn_s[1024];      // group wnorm
  const int t = threadIdx.x;
  const int lane = t & 63;
  const int wid = __builtin_amdgcn_readfirstlane(t >> 6);  // 0..3
  const int g = blockIdx.x & 7;
  const int tok_blk = blockIdx.x >> 3;
  const int trow0 = tok_blk * 128 + wid * 32;
  const int lr = lane & 15, lq = lane >> 4;

  bf8 a[2][4];
  #pragma unroll
  for (int tt = 0; tt < 2; ++tt) {
    const short* ap = A + (size_t)(trow0 + tt * 16 + lr) * 128 + lq * 8;
    #pragma unroll
    for (int s = 0; s < 4; ++s) a[tt][s] = *(const bf8*)(ap + s * 32);
  }

  const short* bsrc = B + (size_t)g * 64 * 2048;

  *(float4*)(wn_s + t * 4) = *(const float4*)(wnorm + g * 1024 + t * 4);
  gload16(bsrc + t * 8, &wbuf[0][0] + t * 8);
  gload16(bsrc + 2048 + t * 8, &wbuf[1][0] + t * 8);
  asm volatile("s_waitcnt vmcnt(1) lgkmcnt(0)" ::: "memory");
  __builtin_amdgcn_s_barrier();

  float d1[8], d2[8]; int i1[8];
  #pragma unroll
  for (int v = 0; v < 8; ++v) { d1[v] = 3.4e38f; d2[v] = 3.4e38f; i1[v] = 0; }

  int cur = 0, stg = 2;
  for (int c = 0; c < 64; ++c) {
    if (c + 2 < 64)
      gload16(bsrc + (c + 2) * 2048 + t * 8, &wbuf[stg][0] + t * 8);

    const short* cb = &wbuf[cur][0];
    bf8 bfr[4];
    #pragma unroll
    for (int s = 0; s < 4; ++s)
      bfr[s] = *(const bf8*)(cb + s * 512 + lq * 128 + lr * 8);
    float wn = wn_s[c * 16 + lr];

    f32x4 acc[2];
    acc[0] = (f32x4)(0.f); acc[1] = (f32x4)(0.f);
    #pragma unroll
    for (int tt = 0; tt < 2; ++tt) {
      acc[tt] = __builtin_amdgcn_mfma_f32_16x16x32_bf16(a[tt][0], bfr[0], acc[tt], 0, 0, 0);
      acc[tt] = __builtin_amdgcn_mfma_f32_16x16x32_bf16(a[tt][1], bfr[1], acc[tt], 0, 0, 0);
      acc[tt] = __builtin_amdgcn_mfma_f32_16x16x32_bf16(a[tt][0], bfr[2], acc[tt], 0, 0, 0);
      acc[tt] = __builtin_amdgcn_mfma_f32_16x16x32_bf16(a[tt][1], bfr[3], acc[tt], 0, 0, 0);
      acc[tt] = __builtin_amdgcn_mfma_f32_16x16x32_bf16(a[tt][2], bfr[0], acc[tt], 0, 0, 0);
      acc[tt] = __builtin_amdgcn_mfma_f32_16x16x32_bf16(a[tt][3], bfr[1], acc[tt], 0, 0, 0);
    }

    const int code = g * 1024 + c * 16 + lr;
    #pragma unroll
    for (int tt = 0; tt < 2; ++tt)
      #pragma unroll
      for (int r = 0; r < 4; ++r) {
        const int v = tt * 4 + r;
        float d = fmaf(-2.f, acc[tt][r], wn);
        // exact top-2 with d1<=d2 invariant: med3 gives new 2nd-min.
        d2[v] = __builtin_amdgcn_fmed3f(d1[v], d2[v], d);
        bool lt = d < d1[v];
        d1[v] = fminf(d1[v], d);
        i1[v] = lt ? code : i1[v];
      }

    if (c < 63) {
      if (c + 2 < 64) asm volatile("s_waitcnt vmcnt(1)" ::: "memory");
      else            asm volatile("s_waitcnt vmcnt(0)" ::: "memory");
      __builtin_amdgcn_s_barrier();
    }
    cur = (cur == 2) ? 0 : cur + 1;
    stg = (stg == 2) ? 0 : stg + 1;
  }

  #pragma unroll
  for (int m = 1; m < 16; m <<= 1) {
    #pragma unroll
    for (int v = 0; v < 8; ++v) {
      float od1 = __shfl_xor(d1[v], m, 64);
      float od2 = __shfl_xor(d2[v], m, 64);
      int   oi1 = __shfl_xor(i1[v], m, 64);
      d2[v] = fminf(fminf(d2[v], od2), fmaxf(d1[v], od1));
      bool take = (od1 < d1[v]) || (od1 == d1[v] && oi1 < i1[v]);
      d1[v] = take ? od1 : d1[v];
      i1[v] = take ? oi1 : i1[v];
    }
  }

  if (lr == 0) {
    #pragma unroll
    for (int tt = 0; tt < 2; ++tt)
      #pragma unroll
      for (int r = 0; r < 4; ++r) {
        int v = tt * 4 + r;
        int token = trow0 + tt * 16 + lq * 4 + r;
        cand[g * N_TOK + token] = d1[v];
        ((int*)cand)[CAND_I1 + g * N_TOK + token] = i1[v];
        cand[CAND_D2 + g * N_TOK + token] = d2[v];
      }
  }
}

// ---------------------------------------------------------------------------
// K2: merge GROUPS candidates (exact 2-min); packed (idx-truth) + margin
// flags; zero counts (B'' dead here; must precede k_enc).
__global__ void k_reduce(const float* __restrict__ cand, int* __restrict__ flags,
                         int* __restrict__ fcnt,
                         unsigned long long* __restrict__ packed,
                         float* __restrict__ cs) {
  int n = blockIdx.x * 256 + threadIdx.x;
  if (n < K_EMB) cs[n] = 0.f;              // counts accumulator zero
  const int* ci = (const int*)cand + CAND_I1;
  float D1 = cand[n]; int I1 = ci[n]; float D2 = cand[CAND_D2 + n];
  #pragma unroll
  for (int g = 1; g < GROUPS; ++g) {
    float d = cand[g * N_TOK + n];
    int   i = ci[g * N_TOK + n];
    float dd = cand[CAND_D2 + g * N_TOK + n];
    D2 = fminf(fminf(D2, dd), fmaxf(D1, d));
    bool take = (d < D1) || (d == D1 && i < I1);
    D1 = take ? d : D1; I1 = take ? i : I1;
  }
  if (D2 - D1 < MARGIN) {
    packed[n] = ~0ull;                     // refine will atomicMin exact vals
    int p = atomicAdd(fcnt, 1);
    flags[p] = n;
  } else {
    unsigned int bits = __float_as_uint(D1);
    unsigned int u = (bits & 0x80000000u) ? ~bits : (bits | 0x80000000u);
    packed[n] = ((unsigned long long)u << 32) | (unsigned int)I1;
  }
}

// ---------------------------------------------------------------------------
// K2b: exact fp32 refine, wave-per-code (R24 structure).
__global__ void k_refine(const float* __restrict__ z, const float* __restrict__ weight,
                         const float* __restrict__ wnorm, const int* __restrict__ flags,
                         const int* __restrict__ fcnt,
                         unsigned long long* __restrict__ packed) {
  const int cnt = *fcnt;
  const int lane = threadIdx.x & 63;
  const int wv = threadIdx.x >> 6;
  for (int w = blockIdx.x; w < cnt * 8; w += gridDim.x) {
    const int f = w >> 3, sub = w & 7;
    const int n = flags[f];
    const int b = n >> 10, hw = n & 1023;
    const float zd = z[b * 65536 + lane * 1024 + hw];
    float bd = 3.4e38f; int bi = 0;
    const int k0 = sub * 1024 + wv * 256;
    #pragma unroll 4
    for (int i = 0; i < 256; ++i) {
      const int k = k0 + i;
      float prod = zd * weight[k * EMB_D + lane];
      #pragma unroll
      for (int off = 32; off > 0; off >>= 1) prod += __shfl_xor(prod, off, 64);
      float dist = fmaf(-2.f, prod, wnorm[k]);
      if (dist < bd) { bd = dist; bi = k; }
    }
    if (lane == 0) {
      unsigned int bits = __float_as_uint(bd);
      unsigned int u = (bits & 0x80000000u) ? ~bits : (bits | 0x80000000u);
      atomicMin(packed + n, ((unsigned long long)u << 32) | (unsigned int)bi);
    }
  }
}

// ---------------------------------------------------------------------------
// K2c: idx + enc counts from packed (post-refine truth).
__global__ void k_enc(const unsigned long long* __restrict__ packed,
                      int* __restrict__ idx, float* __restrict__ cnt) {
  int n = blockIdx.x * 256 + threadIdx.x;
  int k = (int)(packed[n] & 0xffffffffull);
  idx[n] = k;
  atomicAdd(cnt + k, 1.0f);
}

// ---------------------------------------------------------------------------
// K2e: exclusive prefix-sum of counts -> offs + cursors; also nsum
// closed-form: 0.99*sum(cluster_in) + 0.01*N_TOK (sum enc == N_TOK exact).
__global__ void k_scan(const float* __restrict__ cnt,
                       const float* __restrict__ cluster_in,
                       int* __restrict__ offs, int* __restrict__ curs,
                       float* __restrict__ ws) {
  __shared__ int part[256];
  __shared__ float fpart[256];
  const int t = threadIdx.x;
  const int base = t * 32;
  int local[32];
  int s = 0;
  #pragma unroll
  for (int i = 0; i < 32; ++i) { local[i] = s; s += (int)cnt[base + i]; }
  part[t] = s;
  float csl = 0.f;
  #pragma unroll
  for (int i = 0; i < 32; ++i) csl += cluster_in[base + i];
  fpart[t] = csl;
  __syncthreads();
  if (t == 0) {
    int run = 0;
    for (int i = 0; i < 256; ++i) { int v = part[i]; part[i] = run; run += v; }
    float cs2 = 0.f;
    for (int i = 0; i < 256; ++i) cs2 += fpart[i];
    ws[WS_NSUM] = 0.99f * cs2 + 0.01f * (float)N_TOK;
  }
  __syncthreads();
  const int p = part[t];
  #pragma unroll
  for (int i = 0; i < 32; ++i) {
    offs[base + i] = p + local[i];
    curs[base + i] = p + local[i];
  }
}

// ---------------------------------------------------------------------------
// K2f: scatter token ids grouped by code (16K atomics over 8K cursors).
__global__ void k_scatter(const int* __restrict__ idx, int* __restrict__ curs,
                          int* __restrict__ toklist) {
  int n = blockIdx.x * 256 + threadIdx.x;
  int k = idx[n];
  int pos = atomicAdd(curs + k, 1);
  toklist[pos] = n;
}

// ---------------------------------------------------------------------------
// K2g: segmented embed_sum, wave per code, NO atomics. Overwrites EA
// (cand/packed dead). Runs before k_quant overwrites A'.
__global__ void k_embed(const unsigned short* __restrict__ A,
                        const float* __restrict__ cnt,
                        const int* __restrict__ offs,
                        const int* __restrict__ toklist,
                        float* __restrict__ embed) {
  const int lane = threadIdx.x & 63;
  const int k = blockIdx.x * 4 + (threadIdx.x >> 6);
  const int m = (int)cnt[k];
  const int off = offs[k];
  float s = 0.f;
  for (int i = 0; i < m; ++i) {
    const unsigned short* row = A + (size_t)toklist[off + i] * 128;
    s += bf2f(row[lane]) + bf2f(row[64 + lane]);
  }
  embed[k * EMB_D + lane] = s;
}

// ---------------------------------------------------------------------------
// K3: z_q gather + straight-through output + loss partials. x4 vectorized:
// 4 consecutive e = same (b,c), 4 consecutive tokens.
__global__ void k_quant(const float* __restrict__ z, const float* __restrict__ weight,
                        const int* __restrict__ idx, float* __restrict__ out,
                        float* __restrict__ ws) {
  int e0 = (blockIdx.x * 256 + threadIdx.x) * 4;
  int c = (e0 >> 10) & 63;
  int n0 = ((e0 >> 16) << 10) | (e0 & 1023);
  float4 zv = *(const float4*)(z + e0);
  int4 kk = *(const int4*)(idx + n0);
  float4 q;
  q.x = weight[kk.x * EMB_D + c];
  q.y = weight[kk.y * EMB_D + c];
  q.z = weight[kk.z * EMB_D + c];
  q.w = weight[kk.w * EMB_D + c];
  *(float4*)(out + e0) = q;               // straight-through value z+(q-z)=q
  float dx = q.x - zv.x, dy = q.y - zv.y, dz = q.z - zv.z, dw = q.w - zv.w;
  float lsum = dx * dx + dy * dy + dz * dz + dw * dw;
  #pragma unroll
  for (int off = 32; off > 0; off >>= 1) lsum += __shfl_xor(lsum, off, 64);
  __shared__ float red[4];
  int lane = threadIdx.x & 63, wv = threadIdx.x >> 6;
  if (lane == 0) red[wv] = lsum;
  __syncthreads();
  if (threadIdx.x == 0)
    atomicAdd(ws + WS_LOSS, red[0] + red[1] + red[2] + red[3]);
}

// ---------------------------------------------------------------------------
// K5 (fused cluster+final, x4): 4 consecutive e share one k. ncs from raw
// counts; CS written once per k by the (e0&63)==0 thread AFTER block-local
// cnt reads (block owns whole k-groups -> race-free). Loss finalized here.
__global__ void k_final(const float* __restrict__ cluster_in,
                        const float* __restrict__ embed_avg,
                        float* __restrict__ out, const float* __restrict__ ws) {
  int e0 = (blockIdx.x * 256 + threadIdx.x) * 4;   // < 524288
  int k = e0 >> 6;
  float cntk = out[OFF_CS + k];             // raw count
  float ncs = cluster_in[k] * 0.99f + 0.01f * cntk;
  float nsum = ws[WS_NSUM];
  float sm = (ncs + 1e-5f) / (nsum + K_EMB * 1e-5f) * nsum;
  float inv_sm = 1.0f / sm;
  float4 eav = *(const float4*)(embed_avg + e0);
  float4 acc = *(const float4*)(out + OFF_EA + e0);
  float4 ea;
  ea.x = eav.x * 0.99f + 0.01f * acc.x;
  ea.y = eav.y * 0.99f + 0.01f * acc.y;
  ea.z = eav.z * 0.99f + 0.01f * acc.z;
  ea.w = eav.w * 0.99f + 0.01f * acc.w;
  __syncthreads();                          // all cnt reads in block done
  if ((e0 & 63) == 0) out[OFF_CS + k] = ncs;
  *(float4*)(out + OFF_EA + e0) = ea;
  float4 w4;
  w4.x = ea.x * inv_sm; w4.y = ea.y * inv_sm;
  w4.z = ea.z * inv_sm; w4.w = ea.w * inv_sm;
  *(float4*)(out + OFF_W + e0) = w4;
  if (e0 == 0)
    out[OFF_LOSS] = 0.25f * ws[WS_LOSS] * (1.0f / 1048576.0f);
}

// ---------------------------------------------------------------------------
extern "C" void kernel_launch(void* const* d_in, const int* in_sizes, int n_in,
                              void* d_out, int out_size, void* d_ws, size_t ws_size,
                              hipStream_t stream) {
  const float* z = (const float*)d_in[0];
  const float* weight = (const float*)d_in[1];
  const float* cluster = (const float*)d_in[2];
  const float* embed_avg = (const float*)d_in[3];
  float* out = (float*)d_out;
  float* ws = (float*)d_ws;
  float* wnorm = ws + WS_WNORM;
  int* idx = (int*)(ws + WS_IDX);
  int* fcnt = (int*)ws + WS_FCNT;
  const short* Ap = (const short*)out;                     // A' in z_q region
  const short* Bp = (const short*)((unsigned short*)out + B_BASE);
  float* cand = out + OFF_EA;
  unsigned long long* packed = (unsigned long long*)(out + PK_BASE);
  int* flags = (int*)out + SCR_FLAGS;                      // dead-B'' scratch
  int* toklist = (int*)out + SCR_TOK;
  int* offs = (int*)out + SCR_OFFS;
  int* curs = (int*)out + SCR_CURS;

  hipLaunchKernelGGL(k_prep, dim3(576), dim3(256), 0, stream, weight, z, out, ws);
  hipLaunchKernelGGL(k_argmin, dim3(1024), dim3(256), 0, stream,
                     Ap, Bp, wnorm, cand);
  hipLaunchKernelGGL(k_reduce, dim3(N_TOK / 256), dim3(256), 0, stream,
                     cand, flags, fcnt, packed, out + OFF_CS);
  hipLaunchKernelGGL(k_refine, dim3(1024), dim3(256), 0, stream,
                     z, weight, wnorm, flags, fcnt, packed);
  hipLaunchKernelGGL(k_enc, dim3(N_TOK / 256), dim3(256), 0, stream,
                     packed, idx, out + OFF_CS);
  hipLaunchKernelGGL(k_scan, dim3(1), dim3(256), 0, stream,
                     out + OFF_CS, cluster, offs, curs, ws);
  hipLaunchKernelGGL(k_scatter, dim3(N_TOK / 256), dim3(256), 0, stream,
                     idx, curs, toklist);
  hipLaunchKernelGGL(k_embed, dim3(K_EMB / 4), dim3(256), 0, stream,
                     (const unsigned short*)out, out + OFF_CS, offs, toklist,
                     out + OFF_EA);
  hipLaunchKernelGGL(k_quant, dim3(1024), dim3(256), 0, stream,
                     z, weight, idx, out, ws);
  hipLaunchKernelGGL(k_final, dim3(512), dim3(256), 0, stream,
                     cluster, embed_avg, out, ws);
}